// Round 1
// baseline (3129.597 us; speedup 1.0000x reference)
//
#include <hip/hip_runtime.h>
#include <hip/hip_bf16.h>
#include <math.h>

#define NN 50000
#define NE 800000
#define NG 64
#define NEXP 8

#define BK 16
#define BM 64
// BN = 256 (full output width per block)

// ---------------- encoder: h = relu(x @ W_enc + b_enc) -> X1[:, 0:256] ----
__global__ __launch_bounds__(256) void k_encoder(
    const float* __restrict__ x, const float* __restrict__ W,
    const float* __restrict__ b, float* __restrict__ X1) {
  int i = blockIdx.x, n = threadIdx.x;
  float acc = b[n];
#pragma unroll
  for (int k = 0; k < 6; k++) acc = fmaf(x[i * 6 + k], W[k * 256 + n], acc);
  X1[i * 512 + n] = fmaxf(acc, 0.f);
}

// ---------------- per-graph node histogram ----------------
__global__ __launch_bounds__(256) void k_count_nodes(
    const int* __restrict__ batch, int* __restrict__ node_cnt) {
  __shared__ int bins[NG];
  int t = threadIdx.x;
  if (t < NG) bins[t] = 0;
  __syncthreads();
  for (int i = blockIdx.x * blockDim.x + t; i < NN; i += gridDim.x * blockDim.x)
    atomicAdd(&bins[batch[i]], 1);
  __syncthreads();
  if (t < NG) atomicAdd(&node_cnt[t], bins[t]);
}

// ---------------- per-graph edge histogram + in-degree ----------------
__global__ __launch_bounds__(256) void k_count_edges(
    const int* __restrict__ ei, const int* __restrict__ batch,
    int* __restrict__ edge_cnt, int* __restrict__ deg) {
  __shared__ int bins[NG];
  int t = threadIdx.x;
  if (t < NG) bins[t] = 0;
  __syncthreads();
  for (int e = blockIdx.x * blockDim.x + t; e < NE; e += gridDim.x * blockDim.x) {
    int s = ei[e];
    int d = ei[NE + e];
    atomicAdd(&bins[batch[s]], 1);
    atomicAdd(&deg[d], 1);
  }
  __syncthreads();
  if (t < NG) atomicAdd(&edge_cnt[t], bins[t]);
}

// ---------------- size features per node ----------------
__global__ __launch_bounds__(256) void k_sizefeat(
    const int* __restrict__ batch, const int* __restrict__ node_cnt,
    const int* __restrict__ edge_cnt, float* __restrict__ sf0,
    float* __restrict__ sf1) {
  int i = blockIdx.x * blockDim.x + threadIdx.x;
  if (i < NN) {
    int g = batch[i];
    sf0[i] = log1pf((float)node_cnt[g]);
    sf1[i] = log1pf((float)edge_cnt[g]);
  }
}

// ---------------- exclusive prefix scan of deg (single block) ----------------
__global__ __launch_bounds__(1024) void k_scan(
    const int* __restrict__ deg, int* __restrict__ offs, int* __restrict__ cursor) {
  __shared__ int wsums[16];
  int t = threadIdx.x, lane = t & 63, wid = t >> 6;
  int carry = 0;
  for (int base = 0; base < NN; base += 1024) {
    int i = base + t;
    int v = (i < NN) ? deg[i] : 0;
    int x = v;
#pragma unroll
    for (int d = 1; d < 64; d <<= 1) {
      int y = __shfl_up(x, d, 64);
      if (lane >= d) x += y;
    }
    if (lane == 63) wsums[wid] = x;
    __syncthreads();
    if (wid == 0) {
      int s = (lane < 16) ? wsums[lane] : 0;
#pragma unroll
      for (int d = 1; d < 16; d <<= 1) {
        int y = __shfl_up(s, d, 64);
        if (lane >= d) s += y;
      }
      if (lane < 16) wsums[lane] = s;
    }
    __syncthreads();
    int wpre = (wid > 0) ? wsums[wid - 1] : 0;
    int excl = carry + wpre + x - v;
    if (i < NN) { offs[i] = excl; cursor[i] = excl; }
    int btot = wsums[15];
    __syncthreads();
    carry += btot;
  }
  if (t == 0) offs[NN] = carry;
}

// ---------------- CSR fill: bucket edges by dst ----------------
__global__ __launch_bounds__(256) void k_fill_csr(
    const int* __restrict__ ei, int* __restrict__ cursor, int* __restrict__ edge_src) {
  int e = blockIdx.x * blockDim.x + threadIdx.x;
  if (e < NE) {
    int d = ei[NE + e];
    int pos = atomicAdd(&cursor[d], 1);
    edge_src[pos] = ei[e];
  }
}

// ---------------- A_h[i] = sum_{j in Nin(i)} h[j] -> X1[:, 256:512] ----------
__global__ __launch_bounds__(256) void k_agg_h(
    const int* __restrict__ offs, const int* __restrict__ edge_src,
    float* __restrict__ X1) {
  int wid = threadIdx.x >> 6, lane = threadIdx.x & 63;
  int i = blockIdx.x * 4 + wid;
  if (i >= NN) return;
  int e0 = offs[i], e1 = offs[i + 1];
  float4 acc = {0.f, 0.f, 0.f, 0.f};
  for (int e = e0; e < e1; e++) {
    int s = edge_src[e];
    float4 v = *(const float4*)(&X1[s * 512 + lane * 4]);
    acc.x += v.x; acc.y += v.y; acc.z += v.z; acc.w += v.w;
  }
  *(float4*)(&X1[i * 512 + 256 + lane * 4]) = acc;
}

// ---------------- router GEMM: r = relu(h@Wr1[:256] + sf*Wr1[256:258] + br1) ----
__global__ __launch_bounds__(256) void k_router(
    const float* __restrict__ X1, const float* __restrict__ Wr1,
    const float* __restrict__ br1, const float* __restrict__ sf0,
    const float* __restrict__ sf1, float* __restrict__ R) {
  __shared__ float As[BK][BM + 4];
  __shared__ float Bs[BK][256 + 8];
  int t = threadIdx.x;
  int row0 = blockIdx.x * BM;
  int tn = t & 31, tm = t >> 5;
  int arow = t >> 2, akq = (t & 3) * 4;
  int bn4 = (t & 63) * 4, bk0 = (t >> 6) * 4;
  float acc[8][8] = {};
  for (int k0 = 0; k0 < 256; k0 += BK) {
    int gr = row0 + arow;
    float4 va = {0.f, 0.f, 0.f, 0.f};
    if (gr < NN) va = *(const float4*)(&X1[gr * 512 + k0 + akq]);
    As[akq + 0][arow] = va.x; As[akq + 1][arow] = va.y;
    As[akq + 2][arow] = va.z; As[akq + 3][arow] = va.w;
#pragma unroll
    for (int kk = 0; kk < 4; kk++) {
      float4 vb = *(const float4*)(&Wr1[(k0 + bk0 + kk) * 256 + bn4]);
      *(float4*)(&Bs[bk0 + kk][bn4]) = vb;
    }
    __syncthreads();
#pragma unroll
    for (int k = 0; k < BK; k++) {
      float a[8], b[8];
#pragma unroll
      for (int i = 0; i < 8; i++) a[i] = As[k][tm * 8 + i];
#pragma unroll
      for (int j = 0; j < 8; j++) b[j] = Bs[k][tn * 8 + j];
#pragma unroll
      for (int i = 0; i < 8; i++)
#pragma unroll
        for (int j = 0; j < 8; j++) acc[i][j] = fmaf(a[i], b[j], acc[i][j]);
    }
    __syncthreads();
  }
  float4 bb0 = *(const float4*)(&br1[tn * 8]);
  float4 bb1 = *(const float4*)(&br1[tn * 8 + 4]);
  float4 w60 = *(const float4*)(&Wr1[65536 + tn * 8]);      // row 256
  float4 w61 = *(const float4*)(&Wr1[65536 + tn * 8 + 4]);
  float4 w70 = *(const float4*)(&Wr1[65792 + tn * 8]);      // row 257
  float4 w71 = *(const float4*)(&Wr1[65792 + tn * 8 + 4]);
#pragma unroll
  for (int i = 0; i < 8; i++) {
    int r = row0 + tm * 8 + i;
    if (r >= NN) break;
    float s0 = sf0[r], s1 = sf1[r];
    float4 o0, o1;
    o0.x = fmaxf(acc[i][0] + s0 * w60.x + s1 * w70.x + bb0.x, 0.f);
    o0.y = fmaxf(acc[i][1] + s0 * w60.y + s1 * w70.y + bb0.y, 0.f);
    o0.z = fmaxf(acc[i][2] + s0 * w60.z + s1 * w70.z + bb0.z, 0.f);
    o0.w = fmaxf(acc[i][3] + s0 * w60.w + s1 * w70.w + bb0.w, 0.f);
    o1.x = fmaxf(acc[i][4] + s0 * w61.x + s1 * w71.x + bb1.x, 0.f);
    o1.y = fmaxf(acc[i][5] + s0 * w61.y + s1 * w71.y + bb1.y, 0.f);
    o1.z = fmaxf(acc[i][6] + s0 * w61.z + s1 * w71.z + bb1.z, 0.f);
    o1.w = fmaxf(acc[i][7] + s0 * w61.w + s1 * w71.w + bb1.w, 0.f);
    *(float4*)(&R[r * 256 + tn * 8]) = o0;
    *(float4*)(&R[r * 256 + tn * 8 + 4]) = o1;
  }
}

// ---------------- logits + argmax + expert histogram ----------------
__global__ __launch_bounds__(256) void k_logits(
    const float* __restrict__ R, const float* __restrict__ Wr2,
    const float* __restrict__ br2, int* __restrict__ idx, int* __restrict__ ecnt) {
  __shared__ int bins[NEXP];
  int t = threadIdx.x, wid = t >> 6, lane = t & 63;
  if (t < NEXP) bins[t] = 0;
  __syncthreads();
  int i = blockIdx.x * 4 + wid;
  if (i < NN) {
    float4 r4 = *(const float4*)(&R[i * 256 + lane * 4]);
    float rv[4] = {r4.x, r4.y, r4.z, r4.w};
    float acc[NEXP] = {};
#pragma unroll
    for (int kk = 0; kk < 4; kk++) {
      int k = lane * 4 + kk;
#pragma unroll
      for (int e = 0; e < NEXP; e++) acc[e] = fmaf(rv[kk], Wr2[k * 8 + e], acc[e]);
    }
#pragma unroll
    for (int d = 32; d > 0; d >>= 1)
#pragma unroll
      for (int e = 0; e < NEXP; e++) acc[e] += __shfl_xor(acc[e], d, 64);
    if (lane == 0) {
      float best = -1e30f; int bi = 0;
      for (int e = 0; e < NEXP; e++) {
        float v = acc[e] + br2[e];
        if (v > best) { best = v; bi = e; }   // strict > : first-wins, matches jnp.argmax
      }
      idx[i] = bi;
      atomicAdd(&bins[bi], 1);
    }
  }
  __syncthreads();
  if (t < NEXP) atomicAdd(&ecnt[t], bins[t]);
}

__global__ void k_bucket_offs(const int* __restrict__ ecnt,
                              int* __restrict__ boff, int* __restrict__ bcur) {
  if (threadIdx.x == 0) {
    int s = 0;
    for (int e = 0; e < NEXP; e++) { boff[e] = s; bcur[e] = s; s += ecnt[e]; }
    boff[NEXP] = s;
  }
}

__global__ __launch_bounds__(256) void k_bucket_fill(
    const int* __restrict__ idx, int* __restrict__ bcur, int* __restrict__ nlist) {
  int i = blockIdx.x * blockDim.x + threadIdx.x;
  if (i < NN) {
    int pos = atomicAdd(&bcur[idx[i]], 1);
    nlist[pos] = i;
  }
}

// ---------------- layer1 GEMM: z = relu([h|A_h] @ [Ws0_e;Wn0_e] + b0_e) ------
__global__ __launch_bounds__(256) void k_layer1(
    const float* __restrict__ X1, const float* __restrict__ Ws0,
    const float* __restrict__ Wn0, const float* __restrict__ b0,
    int e, float* __restrict__ Z) {
  __shared__ float As[BK][BM + 4];
  __shared__ float Bs[BK][256 + 8];
  int t = threadIdx.x;
  int row0 = blockIdx.x * BM;
  int tn = t & 31, tm = t >> 5;
  int arow = t >> 2, akq = (t & 3) * 4;
  int bn4 = (t & 63) * 4, bk0 = (t >> 6) * 4;
  float acc[8][8] = {};
  for (int k0 = 0; k0 < 512; k0 += BK) {
    int gr = row0 + arow;
    float4 va = {0.f, 0.f, 0.f, 0.f};
    if (gr < NN) va = *(const float4*)(&X1[gr * 512 + k0 + akq]);
    As[akq + 0][arow] = va.x; As[akq + 1][arow] = va.y;
    As[akq + 2][arow] = va.z; As[akq + 3][arow] = va.w;
    const float* Bsrc = (k0 < 256) ? (Ws0 + e * 65536) : (Wn0 + e * 65536);
    int kb = (k0 < 256) ? k0 : (k0 - 256);
#pragma unroll
    for (int kk = 0; kk < 4; kk++) {
      float4 vb = *(const float4*)(&Bsrc[(kb + bk0 + kk) * 256 + bn4]);
      *(float4*)(&Bs[bk0 + kk][bn4]) = vb;
    }
    __syncthreads();
#pragma unroll
    for (int k = 0; k < BK; k++) {
      float a[8], b[8];
#pragma unroll
      for (int i = 0; i < 8; i++) a[i] = As[k][tm * 8 + i];
#pragma unroll
      for (int j = 0; j < 8; j++) b[j] = Bs[k][tn * 8 + j];
#pragma unroll
      for (int i = 0; i < 8; i++)
#pragma unroll
        for (int j = 0; j < 8; j++) acc[i][j] = fmaf(a[i], b[j], acc[i][j]);
    }
    __syncthreads();
  }
  float4 bb0 = *(const float4*)(&b0[e * 256 + tn * 8]);
  float4 bb1 = *(const float4*)(&b0[e * 256 + tn * 8 + 4]);
#pragma unroll
  for (int i = 0; i < 8; i++) {
    int r = row0 + tm * 8 + i;
    if (r >= NN) break;
    float4 o0, o1;
    o0.x = fmaxf(acc[i][0] + bb0.x, 0.f);
    o0.y = fmaxf(acc[i][1] + bb0.y, 0.f);
    o0.z = fmaxf(acc[i][2] + bb0.z, 0.f);
    o0.w = fmaxf(acc[i][3] + bb0.w, 0.f);
    o1.x = fmaxf(acc[i][4] + bb1.x, 0.f);
    o1.y = fmaxf(acc[i][5] + bb1.y, 0.f);
    o1.z = fmaxf(acc[i][6] + bb1.z, 0.f);
    o1.w = fmaxf(acc[i][7] + bb1.w, 0.f);
    *(float4*)(&Z[r * 256 + tn * 8]) = o0;
    *(float4*)(&Z[r * 256 + tn * 8 + 4]) = o1;
  }
}

// ---------------- agg_z for bucket e: AGG[i] = sum z[src], i in bucket -------
__global__ __launch_bounds__(256) void k_agg_z(
    const float* __restrict__ Z, const int* __restrict__ offs,
    const int* __restrict__ edge_src, const int* __restrict__ nlist,
    const int* __restrict__ boff, int e, float* __restrict__ AGG) {
  int wid = threadIdx.x >> 6, lane = threadIdx.x & 63;
  int b = blockIdx.x * 4 + wid;
  int base = boff[e];
  int cnt = boff[e + 1] - base;
  if (b >= cnt) return;
  int i = nlist[base + b];
  int e0 = offs[i], e1 = offs[i + 1];
  float4 acc = {0.f, 0.f, 0.f, 0.f};
  for (int k = e0; k < e1; k++) {
    int s = edge_src[k];
    float4 v = *(const float4*)(&Z[s * 256 + lane * 4]);
    acc.x += v.x; acc.y += v.y; acc.z += v.z; acc.w += v.w;
  }
  *(float4*)(&AGG[i * 256 + lane * 4]) = acc;
}

// ---------------- layer2 gathered GEMM: out[i] = [z_i|agg_i]@[Ws1;Wn1] + b1 --
__global__ __launch_bounds__(256) void k_layer2(
    const float* __restrict__ Z, const float* __restrict__ AGG,
    const float* __restrict__ Ws1, const float* __restrict__ Wn1,
    const float* __restrict__ b1, const int* __restrict__ nlist,
    const int* __restrict__ boff, int e, float* __restrict__ outp) {
  __shared__ float As[BK][BM + 4];
  __shared__ float Bs[BK][256 + 8];
  __shared__ int rows[BM];
  int t = threadIdx.x;
  int m0 = blockIdx.x * BM;
  int base = boff[e];
  int cnt = boff[e + 1] - base;
  if (m0 >= cnt) return;
  if (t < BM) rows[t] = (m0 + t < cnt) ? nlist[base + m0 + t] : -1;
  __syncthreads();
  int tn = t & 31, tm = t >> 5;
  int arow = t >> 2, akq = (t & 3) * 4;
  int bn4 = (t & 63) * 4, bk0 = (t >> 6) * 4;
  float acc[8][8] = {};
  for (int k0 = 0; k0 < 512; k0 += BK) {
    int gr = rows[arow];
    const float* Asrc = (k0 < 256) ? Z : AGG;
    int ka = (k0 < 256) ? k0 : (k0 - 256);
    float4 va = {0.f, 0.f, 0.f, 0.f};
    if (gr >= 0) va = *(const float4*)(&Asrc[gr * 256 + ka + akq]);
    As[akq + 0][arow] = va.x; As[akq + 1][arow] = va.y;
    As[akq + 2][arow] = va.z; As[akq + 3][arow] = va.w;
    const float* Bsrc = (k0 < 256) ? (Ws1 + e * 65536) : (Wn1 + e * 65536);
    int kb = (k0 < 256) ? k0 : (k0 - 256);
#pragma unroll
    for (int kk = 0; kk < 4; kk++) {
      float4 vb = *(const float4*)(&Bsrc[(kb + bk0 + kk) * 256 + bn4]);
      *(float4*)(&Bs[bk0 + kk][bn4]) = vb;
    }
    __syncthreads();
#pragma unroll
    for (int k = 0; k < BK; k++) {
      float a[8], b[8];
#pragma unroll
      for (int i = 0; i < 8; i++) a[i] = As[k][tm * 8 + i];
#pragma unroll
      for (int j = 0; j < 8; j++) b[j] = Bs[k][tn * 8 + j];
#pragma unroll
      for (int i = 0; i < 8; i++)
#pragma unroll
        for (int j = 0; j < 8; j++) acc[i][j] = fmaf(a[i], b[j], acc[i][j]);
    }
    __syncthreads();
  }
  float4 bb0 = *(const float4*)(&b1[e * 256 + tn * 8]);
  float4 bb1 = *(const float4*)(&b1[e * 256 + tn * 8 + 4]);
#pragma unroll
  for (int i = 0; i < 8; i++) {
    int node = rows[tm * 8 + i];
    if (node < 0) break;
    float4 o0, o1;
    o0.x = acc[i][0] + bb0.x; o0.y = acc[i][1] + bb0.y;
    o0.z = acc[i][2] + bb0.z; o0.w = acc[i][3] + bb0.w;
    o1.x = acc[i][4] + bb1.x; o1.y = acc[i][5] + bb1.y;
    o1.z = acc[i][6] + bb1.z; o1.w = acc[i][7] + bb1.w;
    *(float4*)(&outp[node * 256 + tn * 8]) = o0;
    *(float4*)(&outp[node * 256 + tn * 8 + 4]) = o1;
  }
}

static inline char* wsalloc(char*& p, size_t bytes) {
  char* r = p;
  p += (bytes + 255) & ~(size_t)255;
  return r;
}

extern "C" void kernel_launch(void* const* d_in, const int* in_sizes, int n_in,
                              void* d_out, int out_size, void* d_ws, size_t ws_size,
                              hipStream_t stream) {
  const float* x     = (const float*)d_in[0];
  const int*   ei    = (const int*)d_in[1];
  const int*   batch = (const int*)d_in[2];
  const float* W_enc = (const float*)d_in[3];
  const float* b_enc = (const float*)d_in[4];
  const float* Wr1   = (const float*)d_in[5];
  const float* br1   = (const float*)d_in[6];
  const float* Wr2   = (const float*)d_in[7];
  const float* br2   = (const float*)d_in[8];
  const float* Ws0   = (const float*)d_in[9];
  const float* Wn0   = (const float*)d_in[10];
  const float* b0    = (const float*)d_in[11];
  const float* Ws1   = (const float*)d_in[12];
  const float* Wn1   = (const float*)d_in[13];
  const float* b1    = (const float*)d_in[14];
  float* outp = (float*)d_out;

  char* p = (char*)d_ws;
  float* X1     = (float*)wsalloc(p, (size_t)NN * 512 * 4);  // [h | A_h]
  float* Zb     = (float*)wsalloc(p, (size_t)NN * 256 * 4);  // r, then z_e
  int* edge_src = (int*)wsalloc(p, (size_t)NE * 4);
  int* offs     = (int*)wsalloc(p, (size_t)(NN + 1) * 4);
  int* cursor   = (int*)wsalloc(p, (size_t)NN * 4);
  int* deg      = (int*)wsalloc(p, (size_t)NN * 4);
  int* idxb     = (int*)wsalloc(p, (size_t)NN * 4);
  float* sf0    = (float*)wsalloc(p, (size_t)NN * 4);
  float* sf1    = (float*)wsalloc(p, (size_t)NN * 4);
  int* nlist    = (int*)wsalloc(p, (size_t)NN * 4);
  int* smallb   = (int*)wsalloc(p, 256 * 4);
  int* node_cnt = smallb;        // 64
  int* edge_cnt = smallb + 64;   // 64
  int* ecnt     = smallb + 128;  // 8
  int* boff     = smallb + 136;  // 9
  int* bcur     = smallb + 152;  // 8
  float* AGG = outp;             // agg aliases d_out (reads precede writes per row)

  hipMemsetAsync(deg, 0, (size_t)NN * 4, stream);
  hipMemsetAsync(smallb, 0, 256 * 4, stream);

  k_encoder<<<NN, 256, 0, stream>>>(x, W_enc, b_enc, X1);
  k_count_nodes<<<256, 256, 0, stream>>>(batch, node_cnt);
  k_count_edges<<<512, 256, 0, stream>>>(ei, batch, edge_cnt, deg);
  k_sizefeat<<<(NN + 255) / 256, 256, 0, stream>>>(batch, node_cnt, edge_cnt, sf0, sf1);
  k_scan<<<1, 1024, 0, stream>>>(deg, offs, cursor);
  k_fill_csr<<<(NE + 255) / 256, 256, 0, stream>>>(ei, cursor, edge_src);
  k_agg_h<<<(NN + 3) / 4, 256, 0, stream>>>(offs, edge_src, X1);
  k_router<<<(NN + BM - 1) / BM, 256, 0, stream>>>(X1, Wr1, br1, sf0, sf1, Zb);
  k_logits<<<(NN + 3) / 4, 256, 0, stream>>>(Zb, Wr2, br2, idxb, ecnt);
  k_bucket_offs<<<1, 64, 0, stream>>>(ecnt, boff, bcur);
  k_bucket_fill<<<(NN + 255) / 256, 256, 0, stream>>>(idxb, bcur, nlist);
  for (int e = 0; e < NEXP; e++) {
    k_layer1<<<(NN + BM - 1) / BM, 256, 0, stream>>>(X1, Ws0, Wn0, b0, e, Zb);
    k_agg_z<<<(NN + 3) / 4, 256, 0, stream>>>(Zb, offs, edge_src, nlist, boff, e, AGG);
    k_layer2<<<(NN + BM - 1) / BM, 256, 0, stream>>>(Zb, AGG, Ws1, Wn1, b1, nlist, boff, e, outp);
  }
}

// Round 2
// 1388.891 us; speedup vs baseline: 2.2533x; 2.2533x over previous
//
#include <hip/hip_runtime.h>
#include <hip/hip_bf16.h>
#include <math.h>

#define NN 50000
#define NE 800000
#define NG 64
#define NEXP 8

#define BK 16
#define BM 64

typedef __attribute__((ext_vector_type(8))) short bf16x8;
typedef __attribute__((ext_vector_type(4))) float f32x4;
typedef unsigned short ushort_t;

__device__ __forceinline__ unsigned short f2bf(float f) {
  union { float f; unsigned u; } x; x.f = f;
  unsigned r = x.u + 0x7fff + ((x.u >> 16) & 1);  // RNE
  return (unsigned short)(r >> 16);
}

__device__ __forceinline__ void gld16(const void* g, void* l) {
  __builtin_amdgcn_global_load_lds(
      (const __attribute__((address_space(1))) unsigned int*)g,
      (__attribute__((address_space(3))) unsigned int*)l, 16, 0, 0);
}

// ---------------- encoder: h = relu(x @ W_enc + b_enc) -> X1[:, 0:256] ----
__global__ __launch_bounds__(256) void k_encoder(
    const float* __restrict__ x, const float* __restrict__ W,
    const float* __restrict__ b, float* __restrict__ X1) {
  int i = blockIdx.x, n = threadIdx.x;
  float acc = b[n];
#pragma unroll
  for (int k = 0; k < 6; k++) acc = fmaf(x[i * 6 + k], W[k * 256 + n], acc);
  X1[i * 512 + n] = fmaxf(acc, 0.f);
}

// ---------------- per-graph node histogram ----------------
__global__ __launch_bounds__(256) void k_count_nodes(
    const int* __restrict__ batch, int* __restrict__ node_cnt) {
  __shared__ int bins[NG];
  int t = threadIdx.x;
  if (t < NG) bins[t] = 0;
  __syncthreads();
  for (int i = blockIdx.x * blockDim.x + t; i < NN; i += gridDim.x * blockDim.x)
    atomicAdd(&bins[batch[i]], 1);
  __syncthreads();
  if (t < NG) atomicAdd(&node_cnt[t], bins[t]);
}

// ---------------- per-graph edge histogram + in-degree ----------------
__global__ __launch_bounds__(256) void k_count_edges(
    const int* __restrict__ ei, const int* __restrict__ batch,
    int* __restrict__ edge_cnt, int* __restrict__ deg) {
  __shared__ int bins[NG];
  int t = threadIdx.x;
  if (t < NG) bins[t] = 0;
  __syncthreads();
  for (int e = blockIdx.x * blockDim.x + t; e < NE; e += gridDim.x * blockDim.x) {
    int s = ei[e];
    int d = ei[NE + e];
    atomicAdd(&bins[batch[s]], 1);
    atomicAdd(&deg[d], 1);
  }
  __syncthreads();
  if (t < NG) atomicAdd(&edge_cnt[t], bins[t]);
}

// ---------------- size features per node ----------------
__global__ __launch_bounds__(256) void k_sizefeat(
    const int* __restrict__ batch, const int* __restrict__ node_cnt,
    const int* __restrict__ edge_cnt, float* __restrict__ sf0,
    float* __restrict__ sf1) {
  int i = blockIdx.x * blockDim.x + threadIdx.x;
  if (i < NN) {
    int g = batch[i];
    sf0[i] = log1pf((float)node_cnt[g]);
    sf1[i] = log1pf((float)edge_cnt[g]);
  }
}

// ---------------- exclusive prefix scan of deg (single block) ----------------
__global__ __launch_bounds__(1024) void k_scan(
    const int* __restrict__ deg, int* __restrict__ offs, int* __restrict__ cursor) {
  __shared__ int wsums[16];
  int t = threadIdx.x, lane = t & 63, wid = t >> 6;
  int carry = 0;
  for (int base = 0; base < NN; base += 1024) {
    int i = base + t;
    int v = (i < NN) ? deg[i] : 0;
    int x = v;
#pragma unroll
    for (int d = 1; d < 64; d <<= 1) {
      int y = __shfl_up(x, d, 64);
      if (lane >= d) x += y;
    }
    if (lane == 63) wsums[wid] = x;
    __syncthreads();
    if (wid == 0) {
      int s = (lane < 16) ? wsums[lane] : 0;
#pragma unroll
      for (int d = 1; d < 16; d <<= 1) {
        int y = __shfl_up(s, d, 64);
        if (lane >= d) s += y;
      }
      if (lane < 16) wsums[lane] = s;
    }
    __syncthreads();
    int wpre = (wid > 0) ? wsums[wid - 1] : 0;
    int excl = carry + wpre + x - v;
    if (i < NN) { offs[i] = excl; cursor[i] = excl; }
    int btot = wsums[15];
    __syncthreads();
    carry += btot;
  }
  if (t == 0) offs[NN] = carry;
}

// ---------------- CSR fill: bucket edges by dst ----------------
__global__ __launch_bounds__(256) void k_fill_csr(
    const int* __restrict__ ei, int* __restrict__ cursor, int* __restrict__ edge_src) {
  int e = blockIdx.x * blockDim.x + threadIdx.x;
  if (e < NE) {
    int d = ei[NE + e];
    int pos = atomicAdd(&cursor[d], 1);
    edge_src[pos] = ei[e];
  }
}

// ---------------- A_h[i] = sum_{j in Nin(i)} h[j] -> X1[:, 256:512] ----------
__global__ __launch_bounds__(256) void k_agg_h(
    const int* __restrict__ offs, const int* __restrict__ edge_src,
    float* __restrict__ X1) {
  int wid = threadIdx.x >> 6, lane = threadIdx.x & 63;
  int i = blockIdx.x * 4 + wid;
  if (i >= NN) return;
  int e0 = offs[i], e1 = offs[i + 1];
  float4 acc = {0.f, 0.f, 0.f, 0.f};
  for (int e = e0; e < e1; e++) {
    int s = edge_src[e];
    float4 v = *(const float4*)(&X1[s * 512 + lane * 4]);
    acc.x += v.x; acc.y += v.y; acc.z += v.z; acc.w += v.w;
  }
  *(float4*)(&X1[i * 512 + 256 + lane * 4]) = acc;
}

// ---------------- X1 (fp32) -> X1bf (bf16), full [NN,512] ----------------
__global__ __launch_bounds__(256) void k_convert_x(
    const float* __restrict__ X1, ushort_t* __restrict__ Xb) {
  int i = blockIdx.x * 256 + threadIdx.x;  // quad index, NN*512/4 = 6.4M exact
  float4 v = ((const float4*)X1)[i];
  ushort4 o;
  o.x = f2bf(v.x); o.y = f2bf(v.y); o.z = f2bf(v.z); o.w = f2bf(v.w);
  ((ushort4*)Xb)[i] = o;
}

// ------ Wt[e][n][k] (bf16, k=0..511): k<256 -> Ws0[e][k][n], else Wn0 -------
__global__ __launch_bounds__(256) void k_prep_w(
    const float* __restrict__ Ws0, const float* __restrict__ Wn0,
    ushort_t* __restrict__ Wt) {
  __shared__ float tile[32][33];
  int e = blockIdx.z;
  int kt = blockIdx.x;   // 16 k-tiles of 32 (over 512)
  int nt = blockIdx.y;   // 8 n-tiles of 32 (over 256)
  int tx = threadIdx.x & 31, ty = threadIdx.x >> 5;  // 32 x 8
  const float* src = (kt < 8) ? (Ws0 + e * 65536 + (kt * 32) * 256)
                              : (Wn0 + e * 65536 + ((kt - 8) * 32) * 256);
#pragma unroll
  for (int rr = 0; rr < 32; rr += 8) {
    int k = rr + ty;
    tile[k][tx] = src[k * 256 + nt * 32 + tx];
  }
  __syncthreads();
#pragma unroll
  for (int rr = 0; rr < 32; rr += 8) {
    int n = rr + ty;
    Wt[(size_t)e * 131072 + (nt * 32 + n) * 512 + kt * 32 + tx] = f2bf(tile[tx][n]);
  }
}

// ---------------- router GEMM (fp32 — argmax accuracy critical) ----------
__global__ __launch_bounds__(256) void k_router(
    const float* __restrict__ X1, const float* __restrict__ Wr1,
    const float* __restrict__ br1, const float* __restrict__ sf0,
    const float* __restrict__ sf1, float* __restrict__ R) {
  __shared__ float As[BK][BM + 4];
  __shared__ float Bs[BK][256 + 8];
  int t = threadIdx.x;
  int row0 = blockIdx.x * BM;
  int tn = t & 31, tm = t >> 5;
  int arow = t >> 2, akq = (t & 3) * 4;
  int bn4 = (t & 63) * 4, bk0 = (t >> 6) * 4;
  float acc[8][8] = {};
  for (int k0 = 0; k0 < 256; k0 += BK) {
    int gr = row0 + arow;
    float4 va = {0.f, 0.f, 0.f, 0.f};
    if (gr < NN) va = *(const float4*)(&X1[gr * 512 + k0 + akq]);
    As[akq + 0][arow] = va.x; As[akq + 1][arow] = va.y;
    As[akq + 2][arow] = va.z; As[akq + 3][arow] = va.w;
#pragma unroll
    for (int kk = 0; kk < 4; kk++) {
      float4 vb = *(const float4*)(&Wr1[(k0 + bk0 + kk) * 256 + bn4]);
      *(float4*)(&Bs[bk0 + kk][bn4]) = vb;
    }
    __syncthreads();
#pragma unroll
    for (int k = 0; k < BK; k++) {
      float a[8], b[8];
#pragma unroll
      for (int i = 0; i < 8; i++) a[i] = As[k][tm * 8 + i];
#pragma unroll
      for (int j = 0; j < 8; j++) b[j] = Bs[k][tn * 8 + j];
#pragma unroll
      for (int i = 0; i < 8; i++)
#pragma unroll
        for (int j = 0; j < 8; j++) acc[i][j] = fmaf(a[i], b[j], acc[i][j]);
    }
    __syncthreads();
  }
  float4 bb0 = *(const float4*)(&br1[tn * 8]);
  float4 bb1 = *(const float4*)(&br1[tn * 8 + 4]);
  float4 w60 = *(const float4*)(&Wr1[65536 + tn * 8]);
  float4 w61 = *(const float4*)(&Wr1[65536 + tn * 8 + 4]);
  float4 w70 = *(const float4*)(&Wr1[65792 + tn * 8]);
  float4 w71 = *(const float4*)(&Wr1[65792 + tn * 8 + 4]);
#pragma unroll
  for (int i = 0; i < 8; i++) {
    int r = row0 + tm * 8 + i;
    if (r >= NN) break;
    float s0 = sf0[r], s1 = sf1[r];
    float4 o0, o1;
    o0.x = fmaxf(acc[i][0] + s0 * w60.x + s1 * w70.x + bb0.x, 0.f);
    o0.y = fmaxf(acc[i][1] + s0 * w60.y + s1 * w70.y + bb0.y, 0.f);
    o0.z = fmaxf(acc[i][2] + s0 * w60.z + s1 * w70.z + bb0.z, 0.f);
    o0.w = fmaxf(acc[i][3] + s0 * w60.w + s1 * w70.w + bb0.w, 0.f);
    o1.x = fmaxf(acc[i][4] + s0 * w61.x + s1 * w71.x + bb1.x, 0.f);
    o1.y = fmaxf(acc[i][5] + s0 * w61.y + s1 * w71.y + bb1.y, 0.f);
    o1.z = fmaxf(acc[i][6] + s0 * w61.z + s1 * w71.z + bb1.z, 0.f);
    o1.w = fmaxf(acc[i][7] + s0 * w61.w + s1 * w71.w + bb1.w, 0.f);
    *(float4*)(&R[r * 256 + tn * 8]) = o0;
    *(float4*)(&R[r * 256 + tn * 8 + 4]) = o1;
  }
}

// ---------------- logits + argmax + expert histogram ----------------
__global__ __launch_bounds__(256) void k_logits(
    const float* __restrict__ R, const float* __restrict__ Wr2,
    const float* __restrict__ br2, int* __restrict__ idx, int* __restrict__ ecnt) {
  __shared__ int bins[NEXP];
  int t = threadIdx.x, wid = t >> 6, lane = t & 63;
  if (t < NEXP) bins[t] = 0;
  __syncthreads();
  int i = blockIdx.x * 4 + wid;
  if (i < NN) {
    float4 r4 = *(const float4*)(&R[i * 256 + lane * 4]);
    float rv[4] = {r4.x, r4.y, r4.z, r4.w};
    float acc[NEXP] = {};
#pragma unroll
    for (int kk = 0; kk < 4; kk++) {
      int k = lane * 4 + kk;
#pragma unroll
      for (int e = 0; e < NEXP; e++) acc[e] = fmaf(rv[kk], Wr2[k * 8 + e], acc[e]);
    }
#pragma unroll
    for (int d = 32; d > 0; d >>= 1)
#pragma unroll
      for (int e = 0; e < NEXP; e++) acc[e] += __shfl_xor(acc[e], d, 64);
    if (lane == 0) {
      float best = -1e30f; int bi = 0;
      for (int e = 0; e < NEXP; e++) {
        float v = acc[e] + br2[e];
        if (v > best) { best = v; bi = e; }   // strict >: first-wins = jnp.argmax
      }
      idx[i] = bi;
      atomicAdd(&bins[bi], 1);
    }
  }
  __syncthreads();
  if (t < NEXP) atomicAdd(&ecnt[t], bins[t]);
}

__global__ void k_bucket_offs(const int* __restrict__ ecnt,
                              int* __restrict__ boff, int* __restrict__ bcur) {
  if (threadIdx.x == 0) {
    int s = 0;
    for (int e = 0; e < NEXP; e++) { boff[e] = s; bcur[e] = s; s += ecnt[e]; }
    boff[NEXP] = s;
  }
}

// ---- block-aggregated bucket fill: 512 global atomics instead of 50000 ----
#define BF_BLOCKS 64
__global__ __launch_bounds__(256) void k_bucket_fill2(
    const int* __restrict__ idx, int* __restrict__ bcur, int* __restrict__ nlist) {
  __shared__ int lcnt[NEXP];
  __shared__ int lbase[NEXP];
  int t = threadIdx.x;
  int chunk = (NN + BF_BLOCKS - 1) / BF_BLOCKS;
  int lo = blockIdx.x * chunk;
  int hi = lo + chunk; if (hi > NN) hi = NN;
  if (t < NEXP) lcnt[t] = 0;
  __syncthreads();
  for (int i = lo + t; i < hi; i += 256) atomicAdd(&lcnt[idx[i]], 1);
  __syncthreads();
  if (t < NEXP) lbase[t] = atomicAdd(&bcur[t], lcnt[t]);
  __syncthreads();
  if (t < NEXP) lcnt[t] = 0;
  __syncthreads();
  for (int i = lo + t; i < hi; i += 256) {
    int e = idx[i];
    int p = atomicAdd(&lcnt[e], 1);
    nlist[lbase[e] + p] = i;  // order within bucket is irrelevant
  }
}

// ------- layer1 bf16 MFMA: z_e = relu(X1bf @ Wt_e^T + b0_e), m97 structure ---
// 128x128 tile, BK=32, 4 waves (2x2), 4x4 16x16x32 frags per wave.
__global__ __launch_bounds__(256) void k_layer1_mfma(
    const ushort_t* __restrict__ Abf,  // [NN][512] bf16
    const ushort_t* __restrict__ Wt,   // [8][256][512] bf16 (n-major)
    const float* __restrict__ b0, int e, float* __restrict__ Z) {
  __shared__ ushort_t As[128 * 32];  // [row][k] linear, 16B chunks lane-ordered
  __shared__ ushort_t Bs[128 * 32];  // [n][k]
  int t = threadIdx.x;
  int w = t >> 6, lane = t & 63;
  int m0 = blockIdx.x * 128;
  int n0 = blockIdx.y * 128;
  int wm = w >> 1, wn = w & 1;
  const ushort_t* Wb = Wt + (size_t)e * 131072;

  f32x4 acc[4][4] = {};

  for (int kt = 0; kt < 16; kt++) {
    int k0 = kt * 32;
#pragma unroll
    for (int i = 0; i < 2; i++) {
      int c = w * 128 + i * 64 + lane;       // chunk id 0..511
      int r = c >> 2, kc = c & 3;            // row in tile, 8-elem k-chunk
      int gr = m0 + r; if (gr >= NN) gr = NN - 1;   // clamp (junk rows unused)
      gld16(Abf + (size_t)gr * 512 + k0 + kc * 8,
            (void*)&As[(w * 128 + i * 64) * 8]);
      gld16(Wb + (size_t)(n0 + r) * 512 + k0 + kc * 8,
            (void*)&Bs[(w * 128 + i * 64) * 8]);
    }
    __syncthreads();  // drains vmcnt before barrier
    bf16x8 a[4], b[4];
#pragma unroll
    for (int i = 0; i < 4; i++) {
      int ra = wm * 64 + i * 16 + (lane & 15);
      a[i] = *(const bf16x8*)&As[ra * 32 + (lane >> 4) * 8];
      int nb = wn * 64 + i * 16 + (lane & 15);
      b[i] = *(const bf16x8*)&Bs[nb * 32 + (lane >> 4) * 8];
    }
#pragma unroll
    for (int i = 0; i < 4; i++)
#pragma unroll
      for (int j = 0; j < 4; j++)
        acc[i][j] = __builtin_amdgcn_mfma_f32_16x16x32_bf16(a[i], b[j], acc[i][j], 0, 0, 0);
    __syncthreads();
  }
  // C/D layout: col = lane&15, row = (lane>>4)*4 + reg  [m89/m91 verified]
  int q = lane >> 4, c15 = lane & 15;
#pragma unroll
  for (int i = 0; i < 4; i++) {
#pragma unroll
    for (int j = 0; j < 4; j++) {
      int col = n0 + wn * 64 + j * 16 + c15;
      float bias = b0[e * 256 + col];
#pragma unroll
      for (int v = 0; v < 4; v++) {
        int row = m0 + wm * 64 + i * 16 + q * 4 + v;
        if (row < NN) Z[(size_t)row * 256 + col] = fmaxf(acc[i][j][v] + bias, 0.f);
      }
    }
  }
}

// ---------------- agg_z for bucket e ----------------
__global__ __launch_bounds__(256) void k_agg_z(
    const float* __restrict__ Z, const int* __restrict__ offs,
    const int* __restrict__ edge_src, const int* __restrict__ nlist,
    const int* __restrict__ boff, int e, float* __restrict__ AGG) {
  int wid = threadIdx.x >> 6, lane = threadIdx.x & 63;
  int b = blockIdx.x * 4 + wid;
  int base = boff[e];
  int cnt = boff[e + 1] - base;
  if (b >= cnt) return;
  int i = nlist[base + b];
  int e0 = offs[i], e1 = offs[i + 1];
  float4 acc = {0.f, 0.f, 0.f, 0.f};
  for (int k = e0; k < e1; k++) {
    int s = edge_src[k];
    float4 v = *(const float4*)(&Z[s * 256 + lane * 4]);
    acc.x += v.x; acc.y += v.y; acc.z += v.z; acc.w += v.w;
  }
  *(float4*)(&AGG[i * 256 + lane * 4]) = acc;
}

// ---------------- layer2 gathered GEMM (fp32) ----------------
__global__ __launch_bounds__(256) void k_layer2(
    const float* __restrict__ Z, const float* __restrict__ AGG,
    const float* __restrict__ Ws1, const float* __restrict__ Wn1,
    const float* __restrict__ b1, const int* __restrict__ nlist,
    const int* __restrict__ boff, int e, float* __restrict__ outp) {
  __shared__ float As[BK][BM + 4];
  __shared__ float Bs[BK][256 + 8];
  __shared__ int rows[BM];
  int t = threadIdx.x;
  int m0 = blockIdx.x * BM;
  int base = boff[e];
  int cnt = boff[e + 1] - base;
  if (m0 >= cnt) return;
  if (t < BM) rows[t] = (m0 + t < cnt) ? nlist[base + m0 + t] : -1;
  __syncthreads();
  int tn = t & 31, tm = t >> 5;
  int arow = t >> 2, akq = (t & 3) * 4;
  int bn4 = (t & 63) * 4, bk0 = (t >> 6) * 4;
  float acc[8][8] = {};
  for (int k0 = 0; k0 < 512; k0 += BK) {
    int gr = rows[arow];
    const float* Asrc = (k0 < 256) ? Z : AGG;
    int ka = (k0 < 256) ? k0 : (k0 - 256);
    float4 va = {0.f, 0.f, 0.f, 0.f};
    if (gr >= 0) va = *(const float4*)(&Asrc[gr * 256 + ka + akq]);
    As[akq + 0][arow] = va.x; As[akq + 1][arow] = va.y;
    As[akq + 2][arow] = va.z; As[akq + 3][arow] = va.w;
    const float* Bsrc = (k0 < 256) ? (Ws1 + e * 65536) : (Wn1 + e * 65536);
    int kb = (k0 < 256) ? k0 : (k0 - 256);
#pragma unroll
    for (int kk = 0; kk < 4; kk++) {
      float4 vb = *(const float4*)(&Bsrc[(kb + bk0 + kk) * 256 + bn4]);
      *(float4*)(&Bs[bk0 + kk][bn4]) = vb;
    }
    __syncthreads();
#pragma unroll
    for (int k = 0; k < BK; k++) {
      float a[8], b[8];
#pragma unroll
      for (int i = 0; i < 8; i++) a[i] = As[k][tm * 8 + i];
#pragma unroll
      for (int j = 0; j < 8; j++) b[j] = Bs[k][tn * 8 + j];
#pragma unroll
      for (int i = 0; i < 8; i++)
#pragma unroll
        for (int j = 0; j < 8; j++) acc[i][j] = fmaf(a[i], b[j], acc[i][j]);
    }
    __syncthreads();
  }
  float4 bb0 = *(const float4*)(&b1[e * 256 + tn * 8]);
  float4 bb1 = *(const float4*)(&b1[e * 256 + tn * 8 + 4]);
#pragma unroll
  for (int i = 0; i < 8; i++) {
    int node = rows[tm * 8 + i];
    if (node < 0) break;
    float4 o0, o1;
    o0.x = acc[i][0] + bb0.x; o0.y = acc[i][1] + bb0.y;
    o0.z = acc[i][2] + bb0.z; o0.w = acc[i][3] + bb0.w;
    o1.x = acc[i][4] + bb1.x; o1.y = acc[i][5] + bb1.y;
    o1.z = acc[i][6] + bb1.z; o1.w = acc[i][7] + bb1.w;
    *(float4*)(&outp[node * 256 + tn * 8]) = o0;
    *(float4*)(&outp[node * 256 + tn * 8 + 4]) = o1;
  }
}

static inline char* wsalloc(char*& p, size_t bytes) {
  char* r = p;
  p += (bytes + 255) & ~(size_t)255;
  return r;
}

extern "C" void kernel_launch(void* const* d_in, const int* in_sizes, int n_in,
                              void* d_out, int out_size, void* d_ws, size_t ws_size,
                              hipStream_t stream) {
  const float* x     = (const float*)d_in[0];
  const int*   ei    = (const int*)d_in[1];
  const int*   batch = (const int*)d_in[2];
  const float* W_enc = (const float*)d_in[3];
  const float* b_enc = (const float*)d_in[4];
  const float* Wr1   = (const float*)d_in[5];
  const float* br1   = (const float*)d_in[6];
  const float* Wr2   = (const float*)d_in[7];
  const float* br2   = (const float*)d_in[8];
  const float* Ws0   = (const float*)d_in[9];
  const float* Wn0   = (const float*)d_in[10];
  const float* b0    = (const float*)d_in[11];
  const float* Ws1   = (const float*)d_in[12];
  const float* Wn1   = (const float*)d_in[13];
  const float* b1    = (const float*)d_in[14];
  float* outp = (float*)d_out;

  char* p = (char*)d_ws;
  float* X1       = (float*)wsalloc(p, (size_t)NN * 512 * 4);  // [h | A_h] fp32
  float* Zb       = (float*)wsalloc(p, (size_t)NN * 256 * 4);  // r, then z_e
  ushort_t* X1bf  = (ushort_t*)wsalloc(p, (size_t)NN * 512 * 2);
  ushort_t* Wtb   = (ushort_t*)wsalloc(p, (size_t)NEXP * 256 * 512 * 2);
  int* edge_src   = (int*)wsalloc(p, (size_t)NE * 4);
  int* offs       = (int*)wsalloc(p, (size_t)(NN + 1) * 4);
  int* cursor     = (int*)wsalloc(p, (size_t)NN * 4);
  int* deg        = (int*)wsalloc(p, (size_t)NN * 4);
  int* idxb       = (int*)wsalloc(p, (size_t)NN * 4);
  float* sf0      = (float*)wsalloc(p, (size_t)NN * 4);
  float* sf1      = (float*)wsalloc(p, (size_t)NN * 4);
  int* nlist      = (int*)wsalloc(p, (size_t)NN * 4);
  int* smallb     = (int*)wsalloc(p, 256 * 4);
  int* node_cnt = smallb;
  int* edge_cnt = smallb + 64;
  int* ecnt     = smallb + 128;
  int* boff     = smallb + 136;
  int* bcur     = smallb + 152;
  float* AGG = outp;  // aliases d_out: each node written once by layer2 after agg

  hipMemsetAsync(deg, 0, (size_t)NN * 4, stream);
  hipMemsetAsync(smallb, 0, 256 * 4, stream);

  k_encoder<<<NN, 256, 0, stream>>>(x, W_enc, b_enc, X1);
  k_count_nodes<<<256, 256, 0, stream>>>(batch, node_cnt);
  k_count_edges<<<512, 256, 0, stream>>>(ei, batch, edge_cnt, deg);
  k_sizefeat<<<(NN + 255) / 256, 256, 0, stream>>>(batch, node_cnt, edge_cnt, sf0, sf1);
  k_scan<<<1, 1024, 0, stream>>>(deg, offs, cursor);
  k_fill_csr<<<(NE + 255) / 256, 256, 0, stream>>>(ei, cursor, edge_src);
  k_agg_h<<<(NN + 3) / 4, 256, 0, stream>>>(offs, edge_src, X1);
  k_convert_x<<<NN * 512 / 4 / 256, 256, 0, stream>>>(X1, X1bf);
  k_prep_w<<<dim3(16, 8, 8), 256, 0, stream>>>(Ws0, Wn0, Wtb);
  k_router<<<(NN + BM - 1) / BM, 256, 0, stream>>>(X1, Wr1, br1, sf0, sf1, Zb);
  k_logits<<<(NN + 3) / 4, 256, 0, stream>>>(Zb, Wr2, br2, idxb, ecnt);
  k_bucket_offs<<<1, 64, 0, stream>>>(ecnt, boff, bcur);
  k_bucket_fill2<<<BF_BLOCKS, 256, 0, stream>>>(idxb, bcur, nlist);
  for (int e = 0; e < NEXP; e++) {
    k_layer1_mfma<<<dim3((NN + 127) / 128, 2), 256, 0, stream>>>(X1bf, Wtb, b0, e, Zb);
    k_agg_z<<<(NN + 3) / 4, 256, 0, stream>>>(Zb, offs, edge_src, nlist, boff, e, AGG);
    k_layer2<<<(NN + BM - 1) / BM, 256, 0, stream>>>(Zb, AGG, Ws1, Wn1, b1, nlist, boff, e, outp);
  }
}

// Round 3
// 1098.052 us; speedup vs baseline: 2.8501x; 1.2649x over previous
//
#include <hip/hip_runtime.h>
#include <hip/hip_bf16.h>
#include <math.h>

#define NN 50000
#define NE 800000
#define NG 64
#define NEXP 8

#define BK 16
#define BM 64

typedef __attribute__((ext_vector_type(8))) short bf16x8;
typedef __attribute__((ext_vector_type(4))) float f32x4;
typedef unsigned short ushort_t;

__device__ __forceinline__ unsigned short f2bf(float f) {
  union { float f; unsigned u; } x; x.f = f;
  unsigned r = x.u + 0x7fff + ((x.u >> 16) & 1);  // RNE
  return (unsigned short)(r >> 16);
}
__device__ __forceinline__ float bf2f(unsigned short u) {
  union { unsigned u; float f; } x; x.u = ((unsigned)u) << 16; return x.f;
}

__device__ __forceinline__ void gld16(const void* g, void* l) {
  __builtin_amdgcn_global_load_lds(
      (const __attribute__((address_space(1))) unsigned int*)g,
      (__attribute__((address_space(3))) unsigned int*)l, 16, 0, 0);
}

// -------- encoder: h = relu(x@W_enc+b); fp32 copy for router, bf16 for MFMA --
__global__ __launch_bounds__(256) void k_encoder(
    const float* __restrict__ x, const float* __restrict__ W,
    const float* __restrict__ b, float* __restrict__ H32,
    ushort_t* __restrict__ Xb) {
  int i = blockIdx.x, n = threadIdx.x;
  float acc = b[n];
#pragma unroll
  for (int k = 0; k < 6; k++) acc = fmaf(x[i * 6 + k], W[k * 256 + n], acc);
  acc = fmaxf(acc, 0.f);
  H32[i * 256 + n] = acc;
  Xb[(size_t)i * 512 + n] = f2bf(acc);
}

// ---------------- per-graph node histogram ----------------
__global__ __launch_bounds__(256) void k_count_nodes(
    const int* __restrict__ batch, int* __restrict__ node_cnt) {
  __shared__ int bins[NG];
  int t = threadIdx.x;
  if (t < NG) bins[t] = 0;
  __syncthreads();
  for (int i = blockIdx.x * blockDim.x + t; i < NN; i += gridDim.x * blockDim.x)
    atomicAdd(&bins[batch[i]], 1);
  __syncthreads();
  if (t < NG) atomicAdd(&node_cnt[t], bins[t]);
}

// ---------------- per-graph edge histogram + in-degree ----------------
__global__ __launch_bounds__(256) void k_count_edges(
    const int* __restrict__ ei, const int* __restrict__ batch,
    int* __restrict__ edge_cnt, int* __restrict__ deg) {
  __shared__ int bins[NG];
  int t = threadIdx.x;
  if (t < NG) bins[t] = 0;
  __syncthreads();
  for (int e = blockIdx.x * blockDim.x + t; e < NE; e += gridDim.x * blockDim.x) {
    int s = ei[e];
    int d = ei[NE + e];
    atomicAdd(&bins[batch[s]], 1);
    atomicAdd(&deg[d], 1);
  }
  __syncthreads();
  if (t < NG) atomicAdd(&edge_cnt[t], bins[t]);
}

// ---------------- size features per node ----------------
__global__ __launch_bounds__(256) void k_sizefeat(
    const int* __restrict__ batch, const int* __restrict__ node_cnt,
    const int* __restrict__ edge_cnt, float* __restrict__ sf0,
    float* __restrict__ sf1) {
  int i = blockIdx.x * blockDim.x + threadIdx.x;
  if (i < NN) {
    int g = batch[i];
    sf0[i] = log1pf((float)node_cnt[g]);
    sf1[i] = log1pf((float)edge_cnt[g]);
  }
}

// ---------------- exclusive prefix scan of deg (single block) ----------------
__global__ __launch_bounds__(1024) void k_scan(
    const int* __restrict__ deg, int* __restrict__ offs, int* __restrict__ cursor) {
  __shared__ int wsums[16];
  int t = threadIdx.x, lane = t & 63, wid = t >> 6;
  int carry = 0;
  for (int base = 0; base < NN; base += 1024) {
    int i = base + t;
    int v = (i < NN) ? deg[i] : 0;
    int x = v;
#pragma unroll
    for (int d = 1; d < 64; d <<= 1) {
      int y = __shfl_up(x, d, 64);
      if (lane >= d) x += y;
    }
    if (lane == 63) wsums[wid] = x;
    __syncthreads();
    if (wid == 0) {
      int s = (lane < 16) ? wsums[lane] : 0;
#pragma unroll
      for (int d = 1; d < 16; d <<= 1) {
        int y = __shfl_up(s, d, 64);
        if (lane >= d) s += y;
      }
      if (lane < 16) wsums[lane] = s;
    }
    __syncthreads();
    int wpre = (wid > 0) ? wsums[wid - 1] : 0;
    int excl = carry + wpre + x - v;
    if (i < NN) { offs[i] = excl; cursor[i] = excl; }
    int btot = wsums[15];
    __syncthreads();
    carry += btot;
  }
  if (t == 0) offs[NN] = carry;
}

// ---------------- CSR fill: bucket edges by dst ----------------
__global__ __launch_bounds__(256) void k_fill_csr(
    const int* __restrict__ ei, int* __restrict__ cursor, int* __restrict__ edge_src) {
  int e = blockIdx.x * blockDim.x + threadIdx.x;
  if (e < NE) {
    int d = ei[NE + e];
    int pos = atomicAdd(&cursor[d], 1);
    edge_src[pos] = ei[e];
  }
}

// ------- A_h[i] = sum_{j in Nin(i)} h_bf[j] -> Xb[:, 256:512] (bf16) --------
__global__ __launch_bounds__(256) void k_agg_h(
    const int* __restrict__ offs, const int* __restrict__ edge_src,
    ushort_t* __restrict__ Xb) {
  int wid = threadIdx.x >> 6, lane = threadIdx.x & 63;
  int i = blockIdx.x * 4 + wid;
  if (i >= NN) return;
  int e0 = offs[i], e1 = offs[i + 1];
  float acc[4] = {0.f, 0.f, 0.f, 0.f};
  for (int e = e0; e < e1; e++) {
    int s = edge_src[e];
    ushort4 v = *(const ushort4*)(&Xb[(size_t)s * 512 + lane * 4]);
    acc[0] += bf2f(v.x); acc[1] += bf2f(v.y);
    acc[2] += bf2f(v.z); acc[3] += bf2f(v.w);
  }
  ushort4 o;
  o.x = f2bf(acc[0]); o.y = f2bf(acc[1]); o.z = f2bf(acc[2]); o.w = f2bf(acc[3]);
  *(ushort4*)(&Xb[(size_t)i * 512 + 256 + lane * 4]) = o;
}

// ------ Wt[e][n][k] bf16, k in [0,512): k<256 from Ws[e][k][n], else Wn ------
__global__ __launch_bounds__(256) void k_prep_w(
    const float* __restrict__ Ws0, const float* __restrict__ Wn0,
    const float* __restrict__ Ws1, const float* __restrict__ Wn1,
    ushort_t* __restrict__ Wt1, ushort_t* __restrict__ Wt2) {
  __shared__ float tile[32][33];
  int z = blockIdx.z;
  int e = z & 7;
  const float* Ws = (z < 8) ? Ws0 : Ws1;
  const float* Wn = (z < 8) ? Wn0 : Wn1;
  ushort_t* Wt = (z < 8) ? Wt1 : Wt2;
  int kt = blockIdx.x;   // 16 k-tiles of 32 (over 512)
  int nt = blockIdx.y;   // 8 n-tiles of 32 (over 256)
  int tx = threadIdx.x & 31, ty = threadIdx.x >> 5;  // 32 x 8
  const float* src = (kt < 8) ? (Ws + e * 65536 + (kt * 32) * 256)
                              : (Wn + e * 65536 + ((kt - 8) * 32) * 256);
#pragma unroll
  for (int rr = 0; rr < 32; rr += 8) {
    int k = rr + ty;
    tile[k][tx] = src[k * 256 + nt * 32 + tx];
  }
  __syncthreads();
#pragma unroll
  for (int rr = 0; rr < 32; rr += 8) {
    int n = rr + ty;
    Wt[(size_t)e * 131072 + (nt * 32 + n) * 512 + kt * 32 + tx] = f2bf(tile[tx][n]);
  }
}

// ---------------- router GEMM (fp32 — argmax accuracy critical) ----------
__global__ __launch_bounds__(256) void k_router(
    const float* __restrict__ H32, const float* __restrict__ Wr1,
    const float* __restrict__ br1, const float* __restrict__ sf0,
    const float* __restrict__ sf1, float* __restrict__ R) {
  __shared__ float As[BK][BM + 4];
  __shared__ float Bs[BK][256 + 8];
  int t = threadIdx.x;
  int row0 = blockIdx.x * BM;
  int tn = t & 31, tm = t >> 5;
  int arow = t >> 2, akq = (t & 3) * 4;
  int bn4 = (t & 63) * 4, bk0 = (t >> 6) * 4;
  float acc[8][8] = {};
  for (int k0 = 0; k0 < 256; k0 += BK) {
    int gr = row0 + arow;
    float4 va = {0.f, 0.f, 0.f, 0.f};
    if (gr < NN) va = *(const float4*)(&H32[gr * 256 + k0 + akq]);
    As[akq + 0][arow] = va.x; As[akq + 1][arow] = va.y;
    As[akq + 2][arow] = va.z; As[akq + 3][arow] = va.w;
#pragma unroll
    for (int kk = 0; kk < 4; kk++) {
      float4 vb = *(const float4*)(&Wr1[(k0 + bk0 + kk) * 256 + bn4]);
      *(float4*)(&Bs[bk0 + kk][bn4]) = vb;
    }
    __syncthreads();
#pragma unroll
    for (int k = 0; k < BK; k++) {
      float a[8], b[8];
#pragma unroll
      for (int i = 0; i < 8; i++) a[i] = As[k][tm * 8 + i];
#pragma unroll
      for (int j = 0; j < 8; j++) b[j] = Bs[k][tn * 8 + j];
#pragma unroll
      for (int i = 0; i < 8; i++)
#pragma unroll
        for (int j = 0; j < 8; j++) acc[i][j] = fmaf(a[i], b[j], acc[i][j]);
    }
    __syncthreads();
  }
  float4 bb0 = *(const float4*)(&br1[tn * 8]);
  float4 bb1 = *(const float4*)(&br1[tn * 8 + 4]);
  float4 w60 = *(const float4*)(&Wr1[65536 + tn * 8]);
  float4 w61 = *(const float4*)(&Wr1[65536 + tn * 8 + 4]);
  float4 w70 = *(const float4*)(&Wr1[65792 + tn * 8]);
  float4 w71 = *(const float4*)(&Wr1[65792 + tn * 8 + 4]);
#pragma unroll
  for (int i = 0; i < 8; i++) {
    int r = row0 + tm * 8 + i;
    if (r >= NN) break;
    float s0 = sf0[r], s1 = sf1[r];
    float4 o0, o1;
    o0.x = fmaxf(acc[i][0] + s0 * w60.x + s1 * w70.x + bb0.x, 0.f);
    o0.y = fmaxf(acc[i][1] + s0 * w60.y + s1 * w70.y + bb0.y, 0.f);
    o0.z = fmaxf(acc[i][2] + s0 * w60.z + s1 * w70.z + bb0.z, 0.f);
    o0.w = fmaxf(acc[i][3] + s0 * w60.w + s1 * w70.w + bb0.w, 0.f);
    o1.x = fmaxf(acc[i][4] + s0 * w61.x + s1 * w71.x + bb1.x, 0.f);
    o1.y = fmaxf(acc[i][5] + s0 * w61.y + s1 * w71.y + bb1.y, 0.f);
    o1.z = fmaxf(acc[i][6] + s0 * w61.z + s1 * w71.z + bb1.z, 0.f);
    o1.w = fmaxf(acc[i][7] + s0 * w61.w + s1 * w71.w + bb1.w, 0.f);
    *(float4*)(&R[r * 256 + tn * 8]) = o0;
    *(float4*)(&R[r * 256 + tn * 8 + 4]) = o1;
  }
}

// ---------------- logits + argmax + expert histogram ----------------
__global__ __launch_bounds__(256) void k_logits(
    const float* __restrict__ R, const float* __restrict__ Wr2,
    const float* __restrict__ br2, int* __restrict__ idx, int* __restrict__ ecnt) {
  __shared__ int bins[NEXP];
  int t = threadIdx.x, wid = t >> 6, lane = t & 63;
  if (t < NEXP) bins[t] = 0;
  __syncthreads();
  int i = blockIdx.x * 4 + wid;
  if (i < NN) {
    float4 r4 = *(const float4*)(&R[i * 256 + lane * 4]);
    float rv[4] = {r4.x, r4.y, r4.z, r4.w};
    float acc[NEXP] = {};
#pragma unroll
    for (int kk = 0; kk < 4; kk++) {
      int k = lane * 4 + kk;
#pragma unroll
      for (int e = 0; e < NEXP; e++) acc[e] = fmaf(rv[kk], Wr2[k * 8 + e], acc[e]);
    }
#pragma unroll
    for (int d = 32; d > 0; d >>= 1)
#pragma unroll
      for (int e = 0; e < NEXP; e++) acc[e] += __shfl_xor(acc[e], d, 64);
    if (lane == 0) {
      float best = -1e30f; int bi = 0;
      for (int e = 0; e < NEXP; e++) {
        float v = acc[e] + br2[e];
        if (v > best) { best = v; bi = e; }   // strict >: first-wins = jnp.argmax
      }
      idx[i] = bi;
      atomicAdd(&bins[bi], 1);
    }
  }
  __syncthreads();
  if (t < NEXP) atomicAdd(&ecnt[t], bins[t]);
}

// boff/bcur + per-bucket tile starts (128-row tiles for fused layer2)
__global__ void k_bucket_offs(const int* __restrict__ ecnt,
                              int* __restrict__ boff, int* __restrict__ bcur,
                              int* __restrict__ tstart) {
  if (threadIdx.x == 0) {
    int s = 0, ts = 0;
    for (int e = 0; e < NEXP; e++) {
      boff[e] = s; bcur[e] = s;
      tstart[e] = ts;
      ts += (ecnt[e] + 127) / 128;
      s += ecnt[e];
    }
    boff[NEXP] = s;
    tstart[NEXP] = ts;
  }
}

// ---- block-aggregated bucket fill ----
#define BF_BLOCKS 64
__global__ __launch_bounds__(256) void k_bucket_fill2(
    const int* __restrict__ idx, int* __restrict__ bcur, int* __restrict__ nlist) {
  __shared__ int lcnt[NEXP];
  __shared__ int lbase[NEXP];
  int t = threadIdx.x;
  int chunk = (NN + BF_BLOCKS - 1) / BF_BLOCKS;
  int lo = blockIdx.x * chunk;
  int hi = lo + chunk; if (hi > NN) hi = NN;
  if (t < NEXP) lcnt[t] = 0;
  __syncthreads();
  for (int i = lo + t; i < hi; i += 256) atomicAdd(&lcnt[idx[i]], 1);
  __syncthreads();
  if (t < NEXP) lbase[t] = atomicAdd(&bcur[t], lcnt[t]);
  __syncthreads();
  if (t < NEXP) lcnt[t] = 0;
  __syncthreads();
  for (int i = lo + t; i < hi; i += 256) {
    int e = idx[i];
    int p = atomicAdd(&lcnt[e], 1);
    nlist[lbase[e] + p] = i;
  }
}

// ------- layer1 bf16 MFMA: z_e = relu(Xb @ Wt1_e^T + b0_e) -> Zb (bf16) -----
// Also scatters self rows (idx[row]==e) into A2[:, 0:256].
__global__ __launch_bounds__(256) void k_layer1_mfma(
    const ushort_t* __restrict__ Abf,  // [NN][512] bf16
    const ushort_t* __restrict__ Wt,   // [8][256][512] bf16 (n-major)
    const float* __restrict__ b0, const int* __restrict__ idx, int e,
    ushort_t* __restrict__ Zb, ushort_t* __restrict__ A2) {
  __shared__ ushort_t As[128 * 32];
  __shared__ ushort_t Bs[128 * 32];
  __shared__ int sidx[128];
  int t = threadIdx.x;
  int w = t >> 6, lane = t & 63;
  int m0 = blockIdx.x * 128;
  int n0 = blockIdx.y * 128;
  int wm = w >> 1, wn = w & 1;
  const ushort_t* Wb = Wt + (size_t)e * 131072;
  if (t < 128) {
    int r = m0 + t;
    sidx[t] = (r < NN) ? idx[r] : -1;
  }

  f32x4 acc[4][4] = {};

  for (int kt = 0; kt < 16; kt++) {
    int k0 = kt * 32;
#pragma unroll
    for (int i = 0; i < 2; i++) {
      int c = w * 128 + i * 64 + lane;
      int r = c >> 2, kc = c & 3;
      int gr = m0 + r; if (gr >= NN) gr = NN - 1;
      gld16(Abf + (size_t)gr * 512 + k0 + kc * 8,
            (void*)&As[(w * 128 + i * 64) * 8]);
      gld16(Wb + (size_t)(n0 + r) * 512 + k0 + kc * 8,
            (void*)&Bs[(w * 128 + i * 64) * 8]);
    }
    __syncthreads();
    bf16x8 a[4], b[4];
#pragma unroll
    for (int i = 0; i < 4; i++) {
      int ra = wm * 64 + i * 16 + (lane & 15);
      a[i] = *(const bf16x8*)&As[ra * 32 + (lane >> 4) * 8];
      int nb = wn * 64 + i * 16 + (lane & 15);
      b[i] = *(const bf16x8*)&Bs[nb * 32 + (lane >> 4) * 8];
    }
#pragma unroll
    for (int i = 0; i < 4; i++)
#pragma unroll
      for (int j = 0; j < 4; j++)
        acc[i][j] = __builtin_amdgcn_mfma_f32_16x16x32_bf16(a[i], b[j], acc[i][j], 0, 0, 0);
    __syncthreads();
  }
  int q = lane >> 4, c15 = lane & 15;
#pragma unroll
  for (int i = 0; i < 4; i++) {
#pragma unroll
    for (int j = 0; j < 4; j++) {
      int col = n0 + wn * 64 + j * 16 + c15;
      float bias = b0[e * 256 + col];
#pragma unroll
      for (int v = 0; v < 4; v++) {
        int lrow = wm * 64 + i * 16 + q * 4 + v;
        int row = m0 + lrow;
        if (row < NN) {
          unsigned short zb = f2bf(fmaxf(acc[i][j][v] + bias, 0.f));
          Zb[(size_t)row * 256 + col] = zb;
          if (sidx[lrow] == e) A2[(size_t)row * 512 + col] = zb;
        }
      }
    }
  }
}

// ---- agg_z bucket e: A2[i, 256:512] = bf16(sum_{j in Nin(i)} Zb[j]) --------
__global__ __launch_bounds__(256) void k_agg_z(
    const ushort_t* __restrict__ Zb, const int* __restrict__ offs,
    const int* __restrict__ edge_src, const int* __restrict__ nlist,
    const int* __restrict__ boff, int e, ushort_t* __restrict__ A2) {
  int wid = threadIdx.x >> 6, lane = threadIdx.x & 63;
  int b = blockIdx.x * 4 + wid;
  int base = boff[e];
  int cnt = boff[e + 1] - base;
  if (b >= cnt) return;
  int i = nlist[base + b];
  int e0 = offs[i], e1 = offs[i + 1];
  float acc[4] = {0.f, 0.f, 0.f, 0.f};
  for (int k = e0; k < e1; k++) {
    int s = edge_src[k];
    ushort4 v = *(const ushort4*)(&Zb[(size_t)s * 256 + lane * 4]);
    acc[0] += bf2f(v.x); acc[1] += bf2f(v.y);
    acc[2] += bf2f(v.z); acc[3] += bf2f(v.w);
  }
  ushort4 o;
  o.x = f2bf(acc[0]); o.y = f2bf(acc[1]); o.z = f2bf(acc[2]); o.w = f2bf(acc[3]);
  *(ushort4*)(&A2[(size_t)i * 512 + 256 + lane * 4]) = o;
}

// ------- fused layer2 MFMA over all buckets: out = A2_gathered @ W2t_e^T + b1
#define MAXT2 (391 + NEXP)
__global__ __launch_bounds__(256) void k_layer2_mfma(
    const ushort_t* __restrict__ A2,   // [NN][512] bf16
    const ushort_t* __restrict__ Wt,   // [8][256][512] bf16 (n-major)
    const float* __restrict__ b1, const int* __restrict__ nlist,
    const int* __restrict__ boff, const int* __restrict__ tstart,
    float* __restrict__ outp) {
  __shared__ ushort_t As[128 * 32];
  __shared__ ushort_t Bs[128 * 32];
  __shared__ int rows[128];
  int t = threadIdx.x;
  int tx = blockIdx.x;
  int e = -1;
#pragma unroll
  for (int q = 0; q < NEXP; q++)
    if (tx >= tstart[q] && tx < tstart[q + 1]) e = q;
  if (e < 0) return;
  int tile = tx - tstart[e];
  int base = boff[e];
  int cnt = boff[e + 1] - base;
  int m0 = tile * 128;
  if (t < 128) rows[t] = (m0 + t < cnt) ? nlist[base + m0 + t] : -1;
  __syncthreads();
  int w = t >> 6, lane = t & 63;
  int n0 = blockIdx.y * 128;
  int wm = w >> 1, wn = w & 1;
  const ushort_t* Wb = Wt + (size_t)e * 131072;

  f32x4 acc[4][4] = {};

  for (int kt = 0; kt < 16; kt++) {
    int k0 = kt * 32;
#pragma unroll
    for (int i = 0; i < 2; i++) {
      int c = w * 128 + i * 64 + lane;
      int r = c >> 2, kc = c & 3;
      int nd = rows[r]; if (nd < 0) nd = 0;   // junk rows guarded at store
      gld16(A2 + (size_t)nd * 512 + k0 + kc * 8,
            (void*)&As[(w * 128 + i * 64) * 8]);
      gld16(Wb + (size_t)(n0 + r) * 512 + k0 + kc * 8,
            (void*)&Bs[(w * 128 + i * 64) * 8]);
    }
    __syncthreads();
    bf16x8 a[4], b[4];
#pragma unroll
    for (int i = 0; i < 4; i++) {
      int ra = wm * 64 + i * 16 + (lane & 15);
      a[i] = *(const bf16x8*)&As[ra * 32 + (lane >> 4) * 8];
      int nb = wn * 64 + i * 16 + (lane & 15);
      b[i] = *(const bf16x8*)&Bs[nb * 32 + (lane >> 4) * 8];
    }
#pragma unroll
    for (int i = 0; i < 4; i++)
#pragma unroll
      for (int j = 0; j < 4; j++)
        acc[i][j] = __builtin_amdgcn_mfma_f32_16x16x32_bf16(a[i], b[j], acc[i][j], 0, 0, 0);
    __syncthreads();
  }
  int q = lane >> 4, c15 = lane & 15;
#pragma unroll
  for (int i = 0; i < 4; i++) {
#pragma unroll
    for (int j = 0; j < 4; j++) {
      int col = n0 + wn * 64 + j * 16 + c15;
      float bias = b1[e * 256 + col];
#pragma unroll
      for (int v = 0; v < 4; v++) {
        int lrow = wm * 64 + i * 16 + q * 4 + v;
        int node = rows[lrow];
        if (node >= 0) outp[(size_t)node * 256 + col] = acc[i][j][v] + bias;
      }
    }
  }
}

static inline char* wsalloc(char*& p, size_t bytes) {
  char* r = p;
  p += (bytes + 255) & ~(size_t)255;
  return r;
}

extern "C" void kernel_launch(void* const* d_in, const int* in_sizes, int n_in,
                              void* d_out, int out_size, void* d_ws, size_t ws_size,
                              hipStream_t stream) {
  const float* x     = (const float*)d_in[0];
  const int*   ei    = (const int*)d_in[1];
  const int*   batch = (const int*)d_in[2];
  const float* W_enc = (const float*)d_in[3];
  const float* b_enc = (const float*)d_in[4];
  const float* Wr1   = (const float*)d_in[5];
  const float* br1   = (const float*)d_in[6];
  const float* Wr2   = (const float*)d_in[7];
  const float* br2   = (const float*)d_in[8];
  const float* Ws0   = (const float*)d_in[9];
  const float* Wn0   = (const float*)d_in[10];
  const float* b0    = (const float*)d_in[11];
  const float* Ws1   = (const float*)d_in[12];
  const float* Wn1   = (const float*)d_in[13];
  const float* b1    = (const float*)d_in[14];
  float* outp = (float*)d_out;

  char* p = (char*)d_ws;
  float*    H32  = (float*)wsalloc(p, (size_t)NN * 256 * 4);     // fp32 h (router)
  ushort_t* Xb   = (ushort_t*)wsalloc(p, (size_t)NN * 512 * 2);  // [h | A_h] bf16
  ushort_t* Zb   = (ushort_t*)wsalloc(p, (size_t)NN * 256 * 2);  // z_e bf16
  ushort_t* A2   = (ushort_t*)wsalloc(p, (size_t)NN * 512 * 2);  // [z_self | agg] bf16
  float*    R    = (float*)A2;                                   // alias: R dies before A2 born
  ushort_t* Wt1  = (ushort_t*)wsalloc(p, (size_t)NEXP * 256 * 512 * 2);
  ushort_t* Wt2  = (ushort_t*)wsalloc(p, (size_t)NEXP * 256 * 512 * 2);
  int* edge_src  = (int*)wsalloc(p, (size_t)NE * 4);
  int* offs      = (int*)wsalloc(p, (size_t)(NN + 1) * 4);
  int* cursor    = (int*)wsalloc(p, (size_t)NN * 4);
  int* deg       = (int*)wsalloc(p, (size_t)NN * 4);
  int* idxb      = (int*)wsalloc(p, (size_t)NN * 4);
  float* sf0     = (float*)wsalloc(p, (size_t)NN * 4);
  float* sf1     = (float*)wsalloc(p, (size_t)NN * 4);
  int* nlist     = (int*)wsalloc(p, (size_t)NN * 4);
  int* smallb    = (int*)wsalloc(p, 256 * 4);
  int* node_cnt = smallb;        // 64
  int* edge_cnt = smallb + 64;   // 64
  int* ecnt     = smallb + 128;  // 8
  int* boff     = smallb + 136;  // 9
  int* bcur     = smallb + 152;  // 8
  int* tstart   = smallb + 160;  // 9

  hipMemsetAsync(deg, 0, (size_t)NN * 4, stream);
  hipMemsetAsync(smallb, 0, 256 * 4, stream);

  k_encoder<<<NN, 256, 0, stream>>>(x, W_enc, b_enc, H32, Xb);
  k_count_nodes<<<256, 256, 0, stream>>>(batch, node_cnt);
  k_count_edges<<<512, 256, 0, stream>>>(ei, batch, edge_cnt, deg);
  k_sizefeat<<<(NN + 255) / 256, 256, 0, stream>>>(batch, node_cnt, edge_cnt, sf0, sf1);
  k_scan<<<1, 1024, 0, stream>>>(deg, offs, cursor);
  k_fill_csr<<<(NE + 255) / 256, 256, 0, stream>>>(ei, cursor, edge_src);
  k_agg_h<<<(NN + 3) / 4, 256, 0, stream>>>(offs, edge_src, Xb);
  k_prep_w<<<dim3(16, 8, 16), 256, 0, stream>>>(Ws0, Wn0, Ws1, Wn1, Wt1, Wt2);
  k_router<<<(NN + BM - 1) / BM, 256, 0, stream>>>(H32, Wr1, br1, sf0, sf1, R);
  k_logits<<<(NN + 3) / 4, 256, 0, stream>>>(R, Wr2, br2, idxb, ecnt);
  k_bucket_offs<<<1, 64, 0, stream>>>(ecnt, boff, bcur, tstart);
  k_bucket_fill2<<<BF_BLOCKS, 256, 0, stream>>>(idxb, bcur, nlist);
  for (int e = 0; e < NEXP; e++) {
    k_layer1_mfma<<<dim3((NN + 127) / 128, 2), 256, 0, stream>>>(
        Xb, Wt1, b0, idxb, e, Zb, A2);
    k_agg_z<<<(NN + 3) / 4, 256, 0, stream>>>(Zb, offs, edge_src, nlist, boff, e, A2);
  }
  k_layer2_mfma<<<dim3(MAXT2, 2), 256, 0, stream>>>(
      A2, Wt2, b1, nlist, boff, tstart, outp);
}

// Round 4
// 982.618 us; speedup vs baseline: 3.1850x; 1.1175x over previous
//
#include <hip/hip_runtime.h>
#include <hip/hip_bf16.h>
#include <math.h>

#define NN 50000
#define NE 800000
#define NG 64
#define NEXP 8

#define BK 16
#define BM 64

typedef __attribute__((ext_vector_type(8))) short bf16x8;
typedef __attribute__((ext_vector_type(4))) float f32x4;
typedef unsigned short ushort_t;

__device__ __forceinline__ unsigned short f2bf(float f) {
  union { float f; unsigned u; } x; x.f = f;
  unsigned r = x.u + 0x7fff + ((x.u >> 16) & 1);  // RNE
  return (unsigned short)(r >> 16);
}
__device__ __forceinline__ float bf2f(unsigned short u) {
  union { unsigned u; float f; } x; x.u = ((unsigned)u) << 16; return x.f;
}

__device__ __forceinline__ void gld16(const void* g, void* l) {
  __builtin_amdgcn_global_load_lds(
      (const __attribute__((address_space(1))) unsigned int*)g,
      (__attribute__((address_space(3))) unsigned int*)l, 16, 0, 0);
}

// -------- encoder: h = relu(x@W_enc+b); fp32 copy for router, bf16 for MFMA --
__global__ __launch_bounds__(256) void k_encoder(
    const float* __restrict__ x, const float* __restrict__ W,
    const float* __restrict__ b, float* __restrict__ H32,
    ushort_t* __restrict__ Xb) {
  int i = blockIdx.x, n = threadIdx.x;
  float acc = b[n];
#pragma unroll
  for (int k = 0; k < 6; k++) acc = fmaf(x[i * 6 + k], W[k * 256 + n], acc);
  acc = fmaxf(acc, 0.f);
  H32[i * 256 + n] = acc;
  Xb[(size_t)i * 512 + n] = f2bf(acc);
}

// ---------------- per-graph node histogram (64 blocks: tail-atomic light) ----
__global__ __launch_bounds__(256) void k_count_nodes(
    const int* __restrict__ batch, int* __restrict__ node_cnt) {
  __shared__ int bins[NG];
  int t = threadIdx.x;
  if (t < NG) bins[t] = 0;
  __syncthreads();
  for (int i = blockIdx.x * blockDim.x + t; i < NN; i += gridDim.x * blockDim.x)
    atomicAdd(&bins[batch[i]], 1);
  __syncthreads();
  if (t < NG) atomicAdd(&node_cnt[t], bins[t]);
}

// ---------------- per-graph edge histogram + in-degree ----------------
__global__ __launch_bounds__(256) void k_count_edges(
    const int* __restrict__ ei, const int* __restrict__ batch,
    int* __restrict__ edge_cnt, int* __restrict__ deg) {
  __shared__ int bins[NG];
  int t = threadIdx.x;
  if (t < NG) bins[t] = 0;
  __syncthreads();
  for (int e = blockIdx.x * blockDim.x + t; e < NE; e += gridDim.x * blockDim.x) {
    int s = ei[e];
    int d = ei[NE + e];
    atomicAdd(&bins[batch[s]], 1);
    atomicAdd(&deg[d], 1);
  }
  __syncthreads();
  if (t < NG) atomicAdd(&edge_cnt[t], bins[t]);
}

// ---------------- size features per node ----------------
__global__ __launch_bounds__(256) void k_sizefeat(
    const int* __restrict__ batch, const int* __restrict__ node_cnt,
    const int* __restrict__ edge_cnt, float* __restrict__ sf0,
    float* __restrict__ sf1) {
  int i = blockIdx.x * blockDim.x + threadIdx.x;
  if (i < NN) {
    int g = batch[i];
    sf0[i] = log1pf((float)node_cnt[g]);
    sf1[i] = log1pf((float)edge_cnt[g]);
  }
}

// ---------------- exclusive prefix scan of deg (single block) ----------------
__global__ __launch_bounds__(1024) void k_scan(
    const int* __restrict__ deg, int* __restrict__ offs, int* __restrict__ cursor) {
  __shared__ int wsums[16];
  int t = threadIdx.x, lane = t & 63, wid = t >> 6;
  int carry = 0;
  for (int base = 0; base < NN; base += 1024) {
    int i = base + t;
    int v = (i < NN) ? deg[i] : 0;
    int x = v;
#pragma unroll
    for (int d = 1; d < 64; d <<= 1) {
      int y = __shfl_up(x, d, 64);
      if (lane >= d) x += y;
    }
    if (lane == 63) wsums[wid] = x;
    __syncthreads();
    if (wid == 0) {
      int s = (lane < 16) ? wsums[lane] : 0;
#pragma unroll
      for (int d = 1; d < 16; d <<= 1) {
        int y = __shfl_up(s, d, 64);
        if (lane >= d) s += y;
      }
      if (lane < 16) wsums[lane] = s;
    }
    __syncthreads();
    int wpre = (wid > 0) ? wsums[wid - 1] : 0;
    int excl = carry + wpre + x - v;
    if (i < NN) { offs[i] = excl; cursor[i] = excl; }
    int btot = wsums[15];
    __syncthreads();
    carry += btot;
  }
  if (t == 0) offs[NN] = carry;
}

// ---------------- CSR fill: bucket edges by dst ----------------
__global__ __launch_bounds__(256) void k_fill_csr(
    const int* __restrict__ ei, int* __restrict__ cursor, int* __restrict__ edge_src) {
  int e = blockIdx.x * blockDim.x + threadIdx.x;
  if (e < NE) {
    int d = ei[NE + e];
    int pos = atomicAdd(&cursor[d], 1);
    edge_src[pos] = ei[e];
  }
}

// ------- A_h[i] = sum_{j in Nin(i)} h_bf[j] -> Xb[:, 256:512] (bf16) --------
__global__ __launch_bounds__(256) void k_agg_h(
    const int* __restrict__ offs, const int* __restrict__ edge_src,
    ushort_t* __restrict__ Xb) {
  int wid = threadIdx.x >> 6, lane = threadIdx.x & 63;
  int i = blockIdx.x * 4 + wid;
  if (i >= NN) return;
  int e0 = offs[i], e1 = offs[i + 1];
  float acc[4] = {0.f, 0.f, 0.f, 0.f};
  for (int e = e0; e < e1; e++) {
    int s = edge_src[e];
    ushort4 v = *(const ushort4*)(&Xb[(size_t)s * 512 + lane * 4]);
    acc[0] += bf2f(v.x); acc[1] += bf2f(v.y);
    acc[2] += bf2f(v.z); acc[3] += bf2f(v.w);
  }
  ushort4 o;
  o.x = f2bf(acc[0]); o.y = f2bf(acc[1]); o.z = f2bf(acc[2]); o.w = f2bf(acc[3]);
  *(ushort4*)(&Xb[(size_t)i * 512 + 256 + lane * 4]) = o;
}

// ------ Wt[e][n][k] bf16, k in [0,512): k<256 from Ws[e][k][n], else Wn ------
__global__ __launch_bounds__(256) void k_prep_w(
    const float* __restrict__ Ws0, const float* __restrict__ Wn0,
    const float* __restrict__ Ws1, const float* __restrict__ Wn1,
    ushort_t* __restrict__ Wt1, ushort_t* __restrict__ Wt2) {
  __shared__ float tile[32][33];
  int z = blockIdx.z;
  int e = z & 7;
  const float* Ws = (z < 8) ? Ws0 : Ws1;
  const float* Wn = (z < 8) ? Wn0 : Wn1;
  ushort_t* Wt = (z < 8) ? Wt1 : Wt2;
  int kt = blockIdx.x;   // 16 k-tiles of 32 (over 512)
  int nt = blockIdx.y;   // 8 n-tiles of 32 (over 256)
  int tx = threadIdx.x & 31, ty = threadIdx.x >> 5;  // 32 x 8
  const float* src = (kt < 8) ? (Ws + e * 65536 + (kt * 32) * 256)
                              : (Wn + e * 65536 + ((kt - 8) * 32) * 256);
#pragma unroll
  for (int rr = 0; rr < 32; rr += 8) {
    int k = rr + ty;
    tile[k][tx] = src[k * 256 + nt * 32 + tx];
  }
  __syncthreads();
#pragma unroll
  for (int rr = 0; rr < 32; rr += 8) {
    int n = rr + ty;
    Wt[(size_t)e * 131072 + (nt * 32 + n) * 512 + kt * 32 + tx] = f2bf(tile[tx][n]);
  }
}

// ---------------- router GEMM (fp32 — argmax accuracy critical) ----------
__global__ __launch_bounds__(256) void k_router(
    const float* __restrict__ H32, const float* __restrict__ Wr1,
    const float* __restrict__ br1, const float* __restrict__ sf0,
    const float* __restrict__ sf1, float* __restrict__ R) {
  __shared__ float As[BK][BM + 4];
  __shared__ float Bs[BK][256 + 8];
  int t = threadIdx.x;
  int row0 = blockIdx.x * BM;
  int tn = t & 31, tm = t >> 5;
  int arow = t >> 2, akq = (t & 3) * 4;
  int bn4 = (t & 63) * 4, bk0 = (t >> 6) * 4;
  float acc[8][8] = {};
  for (int k0 = 0; k0 < 256; k0 += BK) {
    int gr = row0 + arow;
    float4 va = {0.f, 0.f, 0.f, 0.f};
    if (gr < NN) va = *(const float4*)(&H32[gr * 256 + k0 + akq]);
    As[akq + 0][arow] = va.x; As[akq + 1][arow] = va.y;
    As[akq + 2][arow] = va.z; As[akq + 3][arow] = va.w;
#pragma unroll
    for (int kk = 0; kk < 4; kk++) {
      float4 vb = *(const float4*)(&Wr1[(k0 + bk0 + kk) * 256 + bn4]);
      *(float4*)(&Bs[bk0 + kk][bn4]) = vb;
    }
    __syncthreads();
#pragma unroll
    for (int k = 0; k < BK; k++) {
      float a[8], b[8];
#pragma unroll
      for (int i = 0; i < 8; i++) a[i] = As[k][tm * 8 + i];
#pragma unroll
      for (int j = 0; j < 8; j++) b[j] = Bs[k][tn * 8 + j];
#pragma unroll
      for (int i = 0; i < 8; i++)
#pragma unroll
        for (int j = 0; j < 8; j++) acc[i][j] = fmaf(a[i], b[j], acc[i][j]);
    }
    __syncthreads();
  }
  float4 bb0 = *(const float4*)(&br1[tn * 8]);
  float4 bb1 = *(const float4*)(&br1[tn * 8 + 4]);
  float4 w60 = *(const float4*)(&Wr1[65536 + tn * 8]);
  float4 w61 = *(const float4*)(&Wr1[65536 + tn * 8 + 4]);
  float4 w70 = *(const float4*)(&Wr1[65792 + tn * 8]);
  float4 w71 = *(const float4*)(&Wr1[65792 + tn * 8 + 4]);
#pragma unroll
  for (int i = 0; i < 8; i++) {
    int r = row0 + tm * 8 + i;
    if (r >= NN) break;
    float s0 = sf0[r], s1 = sf1[r];
    float4 o0, o1;
    o0.x = fmaxf(acc[i][0] + s0 * w60.x + s1 * w70.x + bb0.x, 0.f);
    o0.y = fmaxf(acc[i][1] + s0 * w60.y + s1 * w70.y + bb0.y, 0.f);
    o0.z = fmaxf(acc[i][2] + s0 * w60.z + s1 * w70.z + bb0.z, 0.f);
    o0.w = fmaxf(acc[i][3] + s0 * w60.w + s1 * w70.w + bb0.w, 0.f);
    o1.x = fmaxf(acc[i][4] + s0 * w61.x + s1 * w71.x + bb1.x, 0.f);
    o1.y = fmaxf(acc[i][5] + s0 * w61.y + s1 * w71.y + bb1.y, 0.f);
    o1.z = fmaxf(acc[i][6] + s0 * w61.z + s1 * w71.z + bb1.z, 0.f);
    o1.w = fmaxf(acc[i][7] + s0 * w61.w + s1 * w71.w + bb1.w, 0.f);
    *(float4*)(&R[r * 256 + tn * 8]) = o0;
    *(float4*)(&R[r * 256 + tn * 8 + 4]) = o1;
  }
}

// ------ logits + argmax (NO global atomics — histogram moved to k_ecnt) -----
__global__ __launch_bounds__(256) void k_logits(
    const float* __restrict__ R, const float* __restrict__ Wr2,
    const float* __restrict__ br2, int* __restrict__ idx) {
  int t = threadIdx.x, wid = t >> 6, lane = t & 63;
  int i = blockIdx.x * 4 + wid;
  if (i < NN) {
    float4 r4 = *(const float4*)(&R[i * 256 + lane * 4]);
    float rv[4] = {r4.x, r4.y, r4.z, r4.w};
    float acc[NEXP] = {};
#pragma unroll
    for (int kk = 0; kk < 4; kk++) {
      int k = lane * 4 + kk;
#pragma unroll
      for (int e = 0; e < NEXP; e++) acc[e] = fmaf(rv[kk], Wr2[k * 8 + e], acc[e]);
    }
#pragma unroll
    for (int d = 32; d > 0; d >>= 1)
#pragma unroll
      for (int e = 0; e < NEXP; e++) acc[e] += __shfl_xor(acc[e], d, 64);
    if (lane == 0) {
      float best = -1e30f; int bi = 0;
      for (int e = 0; e < NEXP; e++) {
        float v = acc[e] + br2[e];
        if (v > best) { best = v; bi = e; }   // strict >: first-wins = jnp.argmax
      }
      idx[i] = bi;
    }
  }
}

// ------ expert histogram: 64 blocks -> 64 wave-coalesced line-atomics -------
__global__ __launch_bounds__(256) void k_ecnt(
    const int* __restrict__ idx, int* __restrict__ ecnt) {
  __shared__ int bins[NEXP];
  int t = threadIdx.x;
  if (t < NEXP) bins[t] = 0;
  __syncthreads();
  for (int i = blockIdx.x * 256 + t; i < NN; i += gridDim.x * 256)
    atomicAdd(&bins[idx[i]], 1);
  __syncthreads();
  if (t < NEXP) atomicAdd(&ecnt[t], bins[t]);
}

// boff/bcur + per-bucket tile starts (128-row tiles for fused layer2)
__global__ void k_bucket_offs(const int* __restrict__ ecnt,
                              int* __restrict__ boff, int* __restrict__ bcur,
                              int* __restrict__ tstart) {
  if (threadIdx.x == 0) {
    int s = 0, ts = 0;
    for (int e = 0; e < NEXP; e++) {
      boff[e] = s; bcur[e] = s;
      tstart[e] = ts;
      ts += (ecnt[e] + 127) / 128;
      s += ecnt[e];
    }
    boff[NEXP] = s;
    tstart[NEXP] = ts;
  }
}

// ---- block-aggregated bucket fill ----
#define BF_BLOCKS 64
__global__ __launch_bounds__(256) void k_bucket_fill2(
    const int* __restrict__ idx, int* __restrict__ bcur, int* __restrict__ nlist) {
  __shared__ int lcnt[NEXP];
  __shared__ int lbase[NEXP];
  int t = threadIdx.x;
  int chunk = (NN + BF_BLOCKS - 1) / BF_BLOCKS;
  int lo = blockIdx.x * chunk;
  int hi = lo + chunk; if (hi > NN) hi = NN;
  if (t < NEXP) lcnt[t] = 0;
  __syncthreads();
  for (int i = lo + t; i < hi; i += 256) atomicAdd(&lcnt[idx[i]], 1);
  __syncthreads();
  if (t < NEXP) lbase[t] = atomicAdd(&bcur[t], lcnt[t]);
  __syncthreads();
  if (t < NEXP) lcnt[t] = 0;
  __syncthreads();
  for (int i = lo + t; i < hi; i += 256) {
    int e = idx[i];
    int p = atomicAdd(&lcnt[e], 1);
    nlist[lbase[e] + p] = i;
  }
}

// ------- layer1 bf16 MFMA: z_e = relu(Xb @ Wt1_e^T + b0_e) -> Zb (bf16) -----
// Also scatters self rows (idx[row]==e) into A2[:, 0:256].
__global__ __launch_bounds__(256) void k_layer1_mfma(
    const ushort_t* __restrict__ Abf,  // [NN][512] bf16
    const ushort_t* __restrict__ Wt,   // [8][256][512] bf16 (n-major)
    const float* __restrict__ b0, const int* __restrict__ idx, int e,
    ushort_t* __restrict__ Zb, ushort_t* __restrict__ A2) {
  __shared__ ushort_t As[128 * 32];
  __shared__ ushort_t Bs[128 * 32];
  __shared__ int sidx[128];
  int t = threadIdx.x;
  int w = t >> 6, lane = t & 63;
  int m0 = blockIdx.x * 128;
  int n0 = blockIdx.y * 128;
  int wm = w >> 1, wn = w & 1;
  const ushort_t* Wb = Wt + (size_t)e * 131072;
  if (t < 128) {
    int r = m0 + t;
    sidx[t] = (r < NN) ? idx[r] : -1;
  }

  f32x4 acc[4][4] = {};

  for (int kt = 0; kt < 16; kt++) {
    int k0 = kt * 32;
#pragma unroll
    for (int i = 0; i < 2; i++) {
      int c = w * 128 + i * 64 + lane;
      int r = c >> 2, kc = c & 3;
      int gr = m0 + r; if (gr >= NN) gr = NN - 1;
      gld16(Abf + (size_t)gr * 512 + k0 + kc * 8,
            (void*)&As[(w * 128 + i * 64) * 8]);
      gld16(Wb + (size_t)(n0 + r) * 512 + k0 + kc * 8,
            (void*)&Bs[(w * 128 + i * 64) * 8]);
    }
    __syncthreads();
    bf16x8 a[4], b[4];
#pragma unroll
    for (int i = 0; i < 4; i++) {
      int ra = wm * 64 + i * 16 + (lane & 15);
      a[i] = *(const bf16x8*)&As[ra * 32 + (lane >> 4) * 8];
      int nb = wn * 64 + i * 16 + (lane & 15);
      b[i] = *(const bf16x8*)&Bs[nb * 32 + (lane >> 4) * 8];
    }
#pragma unroll
    for (int i = 0; i < 4; i++)
#pragma unroll
      for (int j = 0; j < 4; j++)
        acc[i][j] = __builtin_amdgcn_mfma_f32_16x16x32_bf16(a[i], b[j], acc[i][j], 0, 0, 0);
    __syncthreads();
  }
  int q = lane >> 4, c15 = lane & 15;
#pragma unroll
  for (int i = 0; i < 4; i++) {
#pragma unroll
    for (int j = 0; j < 4; j++) {
      int col = n0 + wn * 64 + j * 16 + c15;
      float bias = b0[e * 256 + col];
#pragma unroll
      for (int v = 0; v < 4; v++) {
        int lrow = wm * 64 + i * 16 + q * 4 + v;
        int row = m0 + lrow;
        if (row < NN) {
          unsigned short zb = f2bf(fmaxf(acc[i][j][v] + bias, 0.f));
          Zb[(size_t)row * 256 + col] = zb;
          if (sidx[lrow] == e) A2[(size_t)row * 512 + col] = zb;
        }
      }
    }
  }
}

// ---- agg_z bucket e: A2[i, 256:512] = bf16(sum_{j in Nin(i)} Zb[j]) --------
__global__ __launch_bounds__(256) void k_agg_z(
    const ushort_t* __restrict__ Zb, const int* __restrict__ offs,
    const int* __restrict__ edge_src, const int* __restrict__ nlist,
    const int* __restrict__ boff, int e, ushort_t* __restrict__ A2) {
  int wid = threadIdx.x >> 6, lane = threadIdx.x & 63;
  int b = blockIdx.x * 4 + wid;
  int base = boff[e];
  int cnt = boff[e + 1] - base;
  if (b >= cnt) return;
  int i = nlist[base + b];
  int e0 = offs[i], e1 = offs[i + 1];
  float acc[4] = {0.f, 0.f, 0.f, 0.f};
  for (int k = e0; k < e1; k++) {
    int s = edge_src[k];
    ushort4 v = *(const ushort4*)(&Zb[(size_t)s * 256 + lane * 4]);
    acc[0] += bf2f(v.x); acc[1] += bf2f(v.y);
    acc[2] += bf2f(v.z); acc[3] += bf2f(v.w);
  }
  ushort4 o;
  o.x = f2bf(acc[0]); o.y = f2bf(acc[1]); o.z = f2bf(acc[2]); o.w = f2bf(acc[3]);
  *(ushort4*)(&A2[(size_t)i * 512 + 256 + lane * 4]) = o;
}

// ------- fused layer2 MFMA over all buckets: out = A2_gathered @ W2t_e^T + b1
#define MAXT2 (391 + NEXP)
__global__ __launch_bounds__(256) void k_layer2_mfma(
    const ushort_t* __restrict__ A2,   // [NN][512] bf16
    const ushort_t* __restrict__ Wt,   // [8][256][512] bf16 (n-major)
    const float* __restrict__ b1, const int* __restrict__ nlist,
    const int* __restrict__ boff, const int* __restrict__ tstart,
    float* __restrict__ outp) {
  __shared__ ushort_t As[128 * 32];
  __shared__ ushort_t Bs[128 * 32];
  __shared__ int rows[128];
  int t = threadIdx.x;
  int tx = blockIdx.x;
  int e = -1;
#pragma unroll
  for (int q = 0; q < NEXP; q++)
    if (tx >= tstart[q] && tx < tstart[q + 1]) e = q;
  if (e < 0) return;
  int tile = tx - tstart[e];
  int base = boff[e];
  int cnt = boff[e + 1] - base;
  int m0 = tile * 128;
  if (t < 128) rows[t] = (m0 + t < cnt) ? nlist[base + m0 + t] : -1;
  __syncthreads();
  int w = t >> 6, lane = t & 63;
  int n0 = blockIdx.y * 128;
  int wm = w >> 1, wn = w & 1;
  const ushort_t* Wb = Wt + (size_t)e * 131072;

  f32x4 acc[4][4] = {};

  for (int kt = 0; kt < 16; kt++) {
    int k0 = kt * 32;
#pragma unroll
    for (int i = 0; i < 2; i++) {
      int c = w * 128 + i * 64 + lane;
      int r = c >> 2, kc = c & 3;
      int nd = rows[r]; if (nd < 0) nd = 0;   // junk rows guarded at store
      gld16(A2 + (size_t)nd * 512 + k0 + kc * 8,
            (void*)&As[(w * 128 + i * 64) * 8]);
      gld16(Wb + (size_t)(n0 + r) * 512 + k0 + kc * 8,
            (void*)&Bs[(w * 128 + i * 64) * 8]);
    }
    __syncthreads();
    bf16x8 a[4], b[4];
#pragma unroll
    for (int i = 0; i < 4; i++) {
      int ra = wm * 64 + i * 16 + (lane & 15);
      a[i] = *(const bf16x8*)&As[ra * 32 + (lane >> 4) * 8];
      int nb = wn * 64 + i * 16 + (lane & 15);
      b[i] = *(const bf16x8*)&Bs[nb * 32 + (lane >> 4) * 8];
    }
#pragma unroll
    for (int i = 0; i < 4; i++)
#pragma unroll
      for (int j = 0; j < 4; j++)
        acc[i][j] = __builtin_amdgcn_mfma_f32_16x16x32_bf16(a[i], b[j], acc[i][j], 0, 0, 0);
    __syncthreads();
  }
  int q = lane >> 4, c15 = lane & 15;
#pragma unroll
  for (int i = 0; i < 4; i++) {
#pragma unroll
    for (int j = 0; j < 4; j++) {
      int col = n0 + wn * 64 + j * 16 + c15;
      float bias = b1[e * 256 + col];
#pragma unroll
      for (int v = 0; v < 4; v++) {
        int lrow = wm * 64 + i * 16 + q * 4 + v;
        int node = rows[lrow];
        if (node >= 0) outp[(size_t)node * 256 + col] = acc[i][j][v] + bias;
      }
    }
  }
}

static inline char* wsalloc(char*& p, size_t bytes) {
  char* r = p;
  p += (bytes + 255) & ~(size_t)255;
  return r;
}

extern "C" void kernel_launch(void* const* d_in, const int* in_sizes, int n_in,
                              void* d_out, int out_size, void* d_ws, size_t ws_size,
                              hipStream_t stream) {
  const float* x     = (const float*)d_in[0];
  const int*   ei    = (const int*)d_in[1];
  const int*   batch = (const int*)d_in[2];
  const float* W_enc = (const float*)d_in[3];
  const float* b_enc = (const float*)d_in[4];
  const float* Wr1   = (const float*)d_in[5];
  const float* br1   = (const float*)d_in[6];
  const float* Wr2   = (const float*)d_in[7];
  const float* br2   = (const float*)d_in[8];
  const float* Ws0   = (const float*)d_in[9];
  const float* Wn0   = (const float*)d_in[10];
  const float* b0    = (const float*)d_in[11];
  const float* Ws1   = (const float*)d_in[12];
  const float* Wn1   = (const float*)d_in[13];
  const float* b1    = (const float*)d_in[14];
  float* outp = (float*)d_out;

  char* p = (char*)d_ws;
  float*    H32  = (float*)wsalloc(p, (size_t)NN * 256 * 4);     // fp32 h (router)
  ushort_t* Xb   = (ushort_t*)wsalloc(p, (size_t)NN * 512 * 2);  // [h | A_h] bf16
  ushort_t* Zb   = (ushort_t*)wsalloc(p, (size_t)NN * 256 * 2);  // z_e bf16
  ushort_t* A2   = (ushort_t*)wsalloc(p, (size_t)NN * 512 * 2);  // [z_self | agg] bf16
  float*    R    = (float*)A2;                                   // alias: R dies before A2 born
  ushort_t* Wt1  = (ushort_t*)wsalloc(p, (size_t)NEXP * 256 * 512 * 2);
  ushort_t* Wt2  = (ushort_t*)wsalloc(p, (size_t)NEXP * 256 * 512 * 2);
  int* edge_src  = (int*)wsalloc(p, (size_t)NE * 4);
  int* offs      = (int*)wsalloc(p, (size_t)(NN + 1) * 4);
  int* cursor    = (int*)wsalloc(p, (size_t)NN * 4);
  int* deg       = (int*)wsalloc(p, (size_t)NN * 4);
  int* idxb      = (int*)wsalloc(p, (size_t)NN * 4);
  float* sf0     = (float*)wsalloc(p, (size_t)NN * 4);
  float* sf1     = (float*)wsalloc(p, (size_t)NN * 4);
  int* nlist     = (int*)wsalloc(p, (size_t)NN * 4);
  int* smallb    = (int*)wsalloc(p, 256 * 4);
  int* node_cnt = smallb;        // 64
  int* edge_cnt = smallb + 64;   // 64
  int* ecnt     = smallb + 128;  // 8
  int* boff     = smallb + 136;  // 9
  int* bcur     = smallb + 152;  // 8
  int* tstart   = smallb + 160;  // 9

  hipMemsetAsync(deg, 0, (size_t)NN * 4, stream);
  hipMemsetAsync(smallb, 0, 256 * 4, stream);

  k_encoder<<<NN, 256, 0, stream>>>(x, W_enc, b_enc, H32, Xb);
  k_count_nodes<<<64, 256, 0, stream>>>(batch, node_cnt);
  k_count_edges<<<128, 256, 0, stream>>>(ei, batch, edge_cnt, deg);
  k_sizefeat<<<(NN + 255) / 256, 256, 0, stream>>>(batch, node_cnt, edge_cnt, sf0, sf1);
  k_scan<<<1, 1024, 0, stream>>>(deg, offs, cursor);
  k_fill_csr<<<(NE + 255) / 256, 256, 0, stream>>>(ei, cursor, edge_src);
  k_agg_h<<<(NN + 3) / 4, 256, 0, stream>>>(offs, edge_src, Xb);
  k_prep_w<<<dim3(16, 8, 16), 256, 0, stream>>>(Ws0, Wn0, Ws1, Wn1, Wt1, Wt2);
  k_router<<<(NN + BM - 1) / BM, 256, 0, stream>>>(H32, Wr1, br1, sf0, sf1, R);
  k_logits<<<(NN + 3) / 4, 256, 0, stream>>>(R, Wr2, br2, idxb);
  k_ecnt<<<64, 256, 0, stream>>>(idxb, ecnt);
  k_bucket_offs<<<1, 64, 0, stream>>>(ecnt, boff, bcur, tstart);
  k_bucket_fill2<<<BF_BLOCKS, 256, 0, stream>>>(idxb, bcur, nlist);
  for (int e = 0; e < NEXP; e++) {
    k_layer1_mfma<<<dim3((NN + 127) / 128, 2), 256, 0, stream>>>(
        Xb, Wt1, b0, idxb, e, Zb, A2);
    k_agg_z<<<(NN + 3) / 4, 256, 0, stream>>>(Zb, offs, edge_src, nlist, boff, e, A2);
  }
  k_layer2_mfma<<<dim3(MAXT2, 2), 256, 0, stream>>>(
      A2, Wt2, b1, nlist, boff, tstart, outp);
}